// Round 2
// baseline (12841.440 us; speedup 1.0000x reference)
//
#include <hip/hip_runtime.h>

// GAT 3-layer forward, ~120 MB workspace.
// Per layer: gemm128 (h = x@W, f32 LDS-tiled) -> node_att (als/ald dots, denom=self term)
// -> edge_denom (atomicAdd exp(lrelu)) -> edge_scatter (recompute alpha, fp32 atomics)
// -> finalize (self term + bias + elu), in place so acc doubles as next x.
// Layer 3 runs in 2 head-pair chunks scattering 0.25*alpha*h straight into d_out.
// segment_max dropped: cancels exactly in alpha=e/denom; logits are O(+-3) here.

#define NEG_SLOPE 0.2f

__device__ __forceinline__ float lrelu(float v) { return v > 0.f ? v : NEG_SLOPE * v; }

// ---------------- diagnostics: workspace overflow sentinel ----------------
__global__ void fill_sentinel(float* __restrict__ out, int n)
{
    int i = blockIdx.x * blockDim.x + threadIdx.x;
    if (i < n) out[i] = 1e30f;
}

// ---------------- edge-index dtype detection (int64 vs int32) ----------------
__global__ void detect_idx64(const int* __restrict__ ei, int* __restrict__ flag)
{
    __shared__ int anynz;
    if (threadIdx.x == 0) anynz = 0;
    __syncthreads();
    int v = ei[2 * threadIdx.x + 1];   // high words if int64 (all values < 2^31)
    if (v != 0) atomicOr(&anynz, 1);
    __syncthreads();
    if (threadIdx.x == 0) flag[0] = (anynz == 0) ? 1 : 0;   // 1 => int64
}

__global__ void convert_edges(const void* __restrict__ ei, const int* __restrict__ flag,
                              int* __restrict__ out, int n)
{
    int i = blockIdx.x * blockDim.x + threadIdx.x;
    if (i >= n) return;
    if (flag[0]) out[i] = (int)((const long long*)ei)[i];
    else         out[i] = ((const int*)ei)[i];
}

// ---------------- GEMM: C[M,128] = A[M,128] @ W[128, wcol0:wcol0+128] ----------------
__global__ __launch_bounds__(256)
void gemm128(const float* __restrict__ A, const float* __restrict__ W,
             float* __restrict__ C, int M, int ldw, int wcol0)
{
    __shared__ float As[128][130];
    __shared__ float Ws[128][132];
    const int m0 = blockIdx.x * 128;
    const int tid = threadIdx.x;

    #pragma unroll
    for (int it = 0; it < 16; ++it) {
        int q = tid + it * 256;
        int row = q >> 5, col = (q & 31) * 4;
        float4 v = make_float4(0.f, 0.f, 0.f, 0.f);
        if (m0 + row < M) v = *(const float4*)&A[(long long)(m0 + row) * 128 + col];
        As[row][col + 0] = v.x; As[row][col + 1] = v.y;
        As[row][col + 2] = v.z; As[row][col + 3] = v.w;
    }
    #pragma unroll
    for (int it = 0; it < 16; ++it) {
        int q = tid + it * 256;
        int k = q >> 5, col = (q & 31) * 4;
        float4 v = *(const float4*)&W[(long long)k * ldw + wcol0 + col];
        *(float4*)&Ws[k][col] = v;
    }
    __syncthreads();

    const int tx = tid & 15, ty = tid >> 4;
    float acc[8][8];
    #pragma unroll
    for (int i = 0; i < 8; ++i)
        #pragma unroll
        for (int j = 0; j < 8; ++j) acc[i][j] = 0.f;

    #pragma unroll 4
    for (int k = 0; k < 128; ++k) {
        float a[8], w[8];
        #pragma unroll
        for (int i = 0; i < 8; ++i) a[i] = As[ty * 8 + i][k];
        float4 w0 = *(const float4*)&Ws[k][tx * 8];
        float4 w1 = *(const float4*)&Ws[k][tx * 8 + 4];
        w[0] = w0.x; w[1] = w0.y; w[2] = w0.z; w[3] = w0.w;
        w[4] = w1.x; w[5] = w1.y; w[6] = w1.z; w[7] = w1.w;
        #pragma unroll
        for (int i = 0; i < 8; ++i)
            #pragma unroll
            for (int j = 0; j < 8; ++j) acc[i][j] += a[i] * w[j];
    }

    #pragma unroll
    for (int i = 0; i < 8; ++i) {
        int gm = m0 + ty * 8 + i;
        if (gm >= M) continue;
        *(float4*)&C[(long long)gm * 128 + tx * 8]     = make_float4(acc[i][0], acc[i][1], acc[i][2], acc[i][3]);
        *(float4*)&C[(long long)gm * 128 + tx * 8 + 4] = make_float4(acc[i][4], acc[i][5], acc[i][6], acc[i][7]);
    }
}

// ---------------- per-node attention coefficients + self-loop denom init ----------------
template<int C, int HL>
__global__ void node_att(const float* __restrict__ h, const float* __restrict__ a_src,
                         const float* __restrict__ a_dst,
                         float* __restrict__ als, float* __restrict__ ald,
                         float* __restrict__ denom, int N)
{
    int t = blockIdx.x * blockDim.x + threadIdx.x;
    if (t >= N * HL) return;
    int n = t / HL, hh = t % HL;
    const float* hp = h + (long long)n * HL * C + hh * C;
    float s1 = 0.f, s2 = 0.f;
    #pragma unroll
    for (int c4 = 0; c4 < C / 4; ++c4) {
        float4 v  = *(const float4*)&hp[c4 * 4];
        float4 a1 = *(const float4*)&a_src[hh * C + c4 * 4];
        float4 a2 = *(const float4*)&a_dst[hh * C + c4 * 4];
        s1 += v.x * a1.x + v.y * a1.y + v.z * a1.z + v.w * a1.w;
        s2 += v.x * a2.x + v.y * a2.y + v.z * a2.z + v.w * a2.w;
    }
    als[t] = s1;
    ald[t] = s2;
    denom[t] = expf(lrelu(s1 + s2));   // self-loop contribution
}

// ---------------- edge pass: denom[d] += exp(lrelu(als[s]+ald[d])) ----------------
template<int HL>
__global__ void edge_denom(const int* __restrict__ src, const int* __restrict__ dst,
                           const float* __restrict__ als, const float* __restrict__ ald,
                           float* __restrict__ denom, int E)
{
    int e = blockIdx.x * blockDim.x + threadIdx.x;
    if (e >= E) return;
    int s = src[e], d = dst[e];
    #pragma unroll
    for (int hh = 0; hh < HL; ++hh) {
        float w = expf(lrelu(als[s * HL + hh] + ald[d * HL + hh]));
        unsafeAtomicAdd(&denom[d * HL + hh], w);
    }
}

// ---------------- edge scatter: out[d] += scale * alpha * h[s] ----------------
template<int C, int HL, bool MEAN>
__global__ void edge_scatter(const int* __restrict__ src, const int* __restrict__ dst,
                             const float* __restrict__ als, const float* __restrict__ ald,
                             const float* __restrict__ denom, const float* __restrict__ h,
                             float* __restrict__ out, int total)
{
    constexpr int PF4 = HL * C / 4;   // float4s per edge
    int t = blockIdx.x * blockDim.x + threadIdx.x;
    if (t >= total) return;
    int e = t / PF4, j = t % PF4;
    int s = src[e], d = dst[e];
    int hh = j / (C / 4), c4 = j % (C / 4);
    float al = expf(lrelu(als[s * HL + hh] + ald[d * HL + hh])) / denom[d * HL + hh];
    float4 hv = *(const float4*)&h[(long long)s * HL * C + j * 4];
    float* op;
    if (MEAN) { al *= 0.25f; op = &out[(long long)d * C + c4 * 4]; }
    else      {              op = &out[(long long)d * HL * C + j * 4]; }
    unsafeAtomicAdd(op + 0, al * hv.x);
    unsafeAtomicAdd(op + 1, al * hv.y);
    unsafeAtomicAdd(op + 2, al * hv.z);
    unsafeAtomicAdd(op + 3, al * hv.w);
}

// ---------------- finalize layers 1-2: acc += self + bias, elu (in place) ----------------
template<int C, int HL>
__global__ void finalize_concat(float* __restrict__ acc, const float* __restrict__ h,
                                const float* __restrict__ als, const float* __restrict__ ald,
                                const float* __restrict__ denom, const float* __restrict__ b,
                                int N)
{
    int t = blockIdx.x * blockDim.x + threadIdx.x;
    if (t >= N * HL * C) return;
    int n = t / (HL * C), j = t % (HL * C), hh = j / C;
    float ws = expf(lrelu(als[n * HL + hh] + ald[n * HL + hh]));
    float v = acc[t] + (ws / denom[n * HL + hh]) * h[t] + b[j];
    acc[t] = v > 0.f ? v : expf(v) - 1.f;   // elu
}

// ---------------- layer-3 chunk: out += 0.25 * self-term for local heads ----------------
template<int C, int HL>
__global__ void add_self_mean(float* __restrict__ out, const float* __restrict__ h,
                              const float* __restrict__ als, const float* __restrict__ ald,
                              const float* __restrict__ denom, int N)
{
    int t = blockIdx.x * blockDim.x + threadIdx.x;
    if (t >= N * C) return;
    int n = t / C, c = t % C;
    float s = 0.f;
    #pragma unroll
    for (int hl = 0; hl < HL; ++hl) {
        float ws = expf(lrelu(als[n * HL + hl] + ald[n * HL + hl]));
        s += (ws / denom[n * HL + hl]) * h[(long long)n * HL * C + hl * C + c];
    }
    out[t] += 0.25f * s;
}

__global__ void add_bias(float* __restrict__ out, const float* __restrict__ b, int total)
{
    int t = blockIdx.x * blockDim.x + threadIdx.x;
    if (t >= total) return;
    out[t] += b[t & 63];
}

extern "C" void kernel_launch(void* const* d_in, const int* in_sizes, int n_in,
                              void* d_out, int out_size, void* d_ws, size_t ws_size,
                              hipStream_t stream)
{
    const float* x      = (const float*)d_in[0];
    const void*  ei     = d_in[1];
    const float* W1     = (const float*)d_in[2];
    const float* a_src1 = (const float*)d_in[3];
    const float* a_dst1 = (const float*)d_in[4];
    const float* b1     = (const float*)d_in[5];
    const float* W2     = (const float*)d_in[6];
    const float* a_src2 = (const float*)d_in[7];
    const float* a_dst2 = (const float*)d_in[8];
    const float* b2     = (const float*)d_in[9];
    const float* W3     = (const float*)d_in[10];
    const float* a_src3 = (const float*)d_in[11];
    const float* a_dst3 = (const float*)d_in[12];
    const float* b3     = (const float*)d_in[13];

    const int N = in_sizes[0] / 128;
    const int E = in_sizes[1] / 2;

    char* w = (char*)d_ws;
    auto alloc = [&](size_t bytes) {
        char* p = w;
        w += (bytes + 255) & ~(size_t)255;
        return p;
    };
    int*   flag  = (int*)  alloc(256);
    int*   edges = (int*)  alloc((size_t)2 * E * 4);   // [2,E] int32
    float* hbuf  = (float*)alloc((size_t)N * 128 * 4);
    float* accb  = (float*)alloc((size_t)N * 128 * 4);
    float* als   = (float*)alloc((size_t)N * 4 * 4);
    float* ald   = (float*)alloc((size_t)N * 4 * 4);
    float* denom = (float*)alloc((size_t)N * 4 * 4);
    if ((size_t)(w - (char*)d_ws) > ws_size) {
        // diagnosable failure: absmax will be ~1e30, not the all-zeros 2.275e-1
        fill_sentinel<<<(out_size + 255) / 256, 256, 0, stream>>>((float*)d_out, out_size);
        return;
    }
    int* src32 = edges;
    int* dst32 = edges + E;

    const int gb = 256;
    const int mb = (N + 127) / 128;
    auto blocks = [&](long long tot) { return (int)((tot + gb - 1) / gb); };

    detect_idx64<<<1, 256, 0, stream>>>((const int*)ei, flag);
    convert_edges<<<blocks(2 * (long long)E), gb, 0, stream>>>(ei, flag, edges, 2 * E);

    // ---------------- layer 1 ----------------
    gemm128<<<mb, gb, 0, stream>>>(x, W1, hbuf, N, 128, 0);
    hipMemsetAsync(accb, 0, (size_t)N * 128 * 4, stream);
    node_att<32, 4><<<blocks(N * 4), gb, 0, stream>>>(hbuf, a_src1, a_dst1, als, ald, denom, N);
    edge_denom<4><<<blocks(E), gb, 0, stream>>>(src32, dst32, als, ald, denom, E);
    edge_scatter<32, 4, false><<<blocks((long long)E * 32), gb, 0, stream>>>(
        src32, dst32, als, ald, denom, hbuf, accb, E * 32);
    finalize_concat<32, 4><<<blocks(N * 128), gb, 0, stream>>>(accb, hbuf, als, ald, denom, b1, N);

    // ---------------- layer 2 (input = accb, in-place from layer 1) ----------------
    gemm128<<<mb, gb, 0, stream>>>(accb, W2, hbuf, N, 128, 0);
    hipMemsetAsync(accb, 0, (size_t)N * 128 * 4, stream);
    node_att<32, 4><<<blocks(N * 4), gb, 0, stream>>>(hbuf, a_src2, a_dst2, als, ald, denom, N);
    edge_denom<4><<<blocks(E), gb, 0, stream>>>(src32, dst32, als, ald, denom, E);
    edge_scatter<32, 4, false><<<blocks((long long)E * 32), gb, 0, stream>>>(
        src32, dst32, als, ald, denom, hbuf, accb, E * 32);
    finalize_concat<32, 4><<<blocks(N * 128), gb, 0, stream>>>(accb, hbuf, als, ald, denom, b2, N);

    // ---------------- layer 3: x = accb; two head-pair chunks into d_out ----------------
    hipMemsetAsync(d_out, 0, (size_t)N * 64 * 4, stream);
    for (int q = 0; q < 2; ++q) {
        gemm128<<<mb, gb, 0, stream>>>(accb, W3, hbuf, N, 256, q * 128);
        node_att<64, 2><<<blocks(N * 2), gb, 0, stream>>>(
            hbuf, a_src3 + q * 128, a_dst3 + q * 128, als, ald, denom, N);
        edge_denom<2><<<blocks(E), gb, 0, stream>>>(src32, dst32, als, ald, denom, E);
        edge_scatter<64, 2, true><<<blocks((long long)E * 32), gb, 0, stream>>>(
            src32, dst32, als, ald, denom, hbuf, (float*)d_out, E * 32);
        add_self_mean<64, 2><<<blocks(N * 64), gb, 0, stream>>>(
            (float*)d_out, hbuf, als, ald, denom, N);
    }
    add_bias<<<blocks(N * 64), gb, 0, stream>>>((float*)d_out, b3, N * 64);
}

// Round 3
// 1565.000 us; speedup vs baseline: 8.2054x; 8.2054x over previous
//
#include <hip/hip_runtime.h>

// GAT 3-layer forward, atomic-free aggregation via per-call CSR build.
// Per layer: gemm128 (h = x@W) -> node_att (als/ald dots) -> gat_aggregate:
//   one WAVE per dst node: out[d] = (sum_e w_e h[src_e] + w_self h[d]) / (sum w + w_self)
//   (normalization is linear -> single pass, registers only, no atomics, no memsets)
// Layer 3 runs as 2 head-pair chunks; head-mean via __shfl_xor(32) pair sum into d_out.
// segment_max dropped: cancels exactly in alpha = e/denom; logits are O(+-3) here.

#define NEG_SLOPE 0.2f

__device__ __forceinline__ float lrelu(float v) { return v > 0.f ? v : NEG_SLOPE * v; }

// ---------------- diagnostics: workspace overflow sentinel ----------------
__global__ void fill_sentinel(float* __restrict__ out, int n)
{
    int i = blockIdx.x * blockDim.x + threadIdx.x;
    if (i < n) out[i] = 1e30f;
}

// ---------------- edge-index dtype detection (int64 vs int32) ----------------
__global__ void detect_idx64(const int* __restrict__ ei, int* __restrict__ flag)
{
    __shared__ int anynz;
    if (threadIdx.x == 0) anynz = 0;
    __syncthreads();
    int v = ei[2 * threadIdx.x + 1];   // high words if int64 (all values < 2^31)
    if (v != 0) atomicOr(&anynz, 1);
    __syncthreads();
    if (threadIdx.x == 0) flag[0] = (anynz == 0) ? 1 : 0;   // 1 => int64
}

// ---------------- CSR build: degree count / scan / fill ----------------
__global__ void count_deg(const void* __restrict__ ei, const int* __restrict__ flag,
                          int* __restrict__ deg, int E)
{
    int e = blockIdx.x * blockDim.x + threadIdx.x;
    if (e >= E) return;
    int d = flag[0] ? (int)((const long long*)ei)[E + e] : ((const int*)ei)[E + e];
    atomicAdd(&deg[d], 1);
}

__global__ __launch_bounds__(1024)
void scan_deg(const int* __restrict__ deg, int* __restrict__ rowptr,
              int* __restrict__ cursor, int N)
{
    __shared__ int part[1024];
    const int t = threadIdx.x;
    const int chunk = (N + 1023) / 1024;
    const int lo = min(t * chunk, N), hi = min(lo + chunk, N);
    int s = 0;
    for (int i = lo; i < hi; ++i) s += deg[i];
    part[t] = s;
    __syncthreads();
    for (int off = 1; off < 1024; off <<= 1) {
        int v = (t >= off) ? part[t - off] : 0;
        __syncthreads();
        part[t] += v;
        __syncthreads();
    }
    int run = (t == 0) ? 0 : part[t - 1];
    for (int i = lo; i < hi; ++i) {
        rowptr[i] = run;
        cursor[i] = run;
        run += deg[i];
    }
    if (hi == N) rowptr[N] = run;   // threads past the end hold run == E too
}

__global__ void fill_csr(const void* __restrict__ ei, const int* __restrict__ flag,
                         int* __restrict__ cursor, int* __restrict__ csr_src, int E)
{
    int e = blockIdx.x * blockDim.x + threadIdx.x;
    if (e >= E) return;
    int s, d;
    if (flag[0]) { s = (int)((const long long*)ei)[e]; d = (int)((const long long*)ei)[E + e]; }
    else         { s = ((const int*)ei)[e];            d = ((const int*)ei)[E + e]; }
    int pos = atomicAdd(&cursor[d], 1);
    csr_src[pos] = s;
}

// ---------------- GEMM: C[M,128] = A[M,128] @ W[128, wcol0:wcol0+128] ----------------
__global__ __launch_bounds__(256)
void gemm128(const float* __restrict__ A, const float* __restrict__ W,
             float* __restrict__ C, int M, int ldw, int wcol0)
{
    __shared__ float As[128][130];
    __shared__ float Ws[128][132];
    const int m0 = blockIdx.x * 128;
    const int tid = threadIdx.x;

    #pragma unroll
    for (int it = 0; it < 16; ++it) {
        int q = tid + it * 256;
        int row = q >> 5, col = (q & 31) * 4;
        float4 v = make_float4(0.f, 0.f, 0.f, 0.f);
        if (m0 + row < M) v = *(const float4*)&A[(long long)(m0 + row) * 128 + col];
        As[row][col + 0] = v.x; As[row][col + 1] = v.y;
        As[row][col + 2] = v.z; As[row][col + 3] = v.w;
    }
    #pragma unroll
    for (int it = 0; it < 16; ++it) {
        int q = tid + it * 256;
        int k = q >> 5, col = (q & 31) * 4;
        float4 v = *(const float4*)&W[(long long)k * ldw + wcol0 + col];
        *(float4*)&Ws[k][col] = v;
    }
    __syncthreads();

    const int tx = tid & 15, ty = tid >> 4;
    float acc[8][8];
    #pragma unroll
    for (int i = 0; i < 8; ++i)
        #pragma unroll
        for (int j = 0; j < 8; ++j) acc[i][j] = 0.f;

    #pragma unroll 4
    for (int k = 0; k < 128; ++k) {
        float a[8], w[8];
        #pragma unroll
        for (int i = 0; i < 8; ++i) a[i] = As[ty * 8 + i][k];
        float4 w0 = *(const float4*)&Ws[k][tx * 8];
        float4 w1 = *(const float4*)&Ws[k][tx * 8 + 4];
        w[0] = w0.x; w[1] = w0.y; w[2] = w0.z; w[3] = w0.w;
        w[4] = w1.x; w[5] = w1.y; w[6] = w1.z; w[7] = w1.w;
        #pragma unroll
        for (int i = 0; i < 8; ++i)
            #pragma unroll
            for (int j = 0; j < 8; ++j) acc[i][j] += a[i] * w[j];
    }

    #pragma unroll
    for (int i = 0; i < 8; ++i) {
        int gm = m0 + ty * 8 + i;
        if (gm >= M) continue;
        *(float4*)&C[(long long)gm * 128 + tx * 8]     = make_float4(acc[i][0], acc[i][1], acc[i][2], acc[i][3]);
        *(float4*)&C[(long long)gm * 128 + tx * 8 + 4] = make_float4(acc[i][4], acc[i][5], acc[i][6], acc[i][7]);
    }
}

// ---------------- per-node attention coefficients ----------------
template<int C, int HL>
__global__ void node_att(const float* __restrict__ h, const float* __restrict__ a_src,
                         const float* __restrict__ a_dst,
                         float* __restrict__ als, float* __restrict__ ald, int N)
{
    int t = blockIdx.x * blockDim.x + threadIdx.x;
    if (t >= N * HL) return;
    int n = t / HL, hh = t % HL;
    const float* hp = h + (long long)n * HL * C + hh * C;
    float s1 = 0.f, s2 = 0.f;
    #pragma unroll
    for (int c4 = 0; c4 < C / 4; ++c4) {
        float4 v  = *(const float4*)&hp[c4 * 4];
        float4 a1 = *(const float4*)&a_src[hh * C + c4 * 4];
        float4 a2 = *(const float4*)&a_dst[hh * C + c4 * 4];
        s1 += v.x * a1.x + v.y * a1.y + v.z * a1.z + v.w * a1.w;
        s2 += v.x * a2.x + v.y * a2.y + v.z * a2.z + v.w * a2.w;
    }
    als[t] = s1;
    ald[t] = s2;
}

// ---------------- fused aggregate: one wave per dst node ----------------
// ROW = HL*C = 128 floats; lane owns float2 at col j = lane*2.
// concat (MEAN=false): out[d] = elu(vec/denom + bias)          (out is [N,128])
// mean   (MEAN=true) : out[d] (+)= 0.25 * headpair_sum(vec/denom) (+ bias if ACCUM)
template<int C, int HL, bool MEAN, bool ACCUM>
__global__ __launch_bounds__(256)
void gat_aggregate(const int* __restrict__ rowptr, const int* __restrict__ csr_src,
                   const float* __restrict__ als, const float* __restrict__ ald,
                   const float* __restrict__ h, const float* __restrict__ bias,
                   float* __restrict__ out, int N)
{
    constexpr int ROW = HL * C;   // 128
    const int d = (blockIdx.x * blockDim.x + threadIdx.x) >> 6;
    const int lane = threadIdx.x & 63;
    if (d >= N) return;
    const int j = lane * 2;
    const int hh = j / C;

    const float ald_d = ald[d * HL + hh];
    const float wself = expf(lrelu(als[d * HL + hh] + ald_d));
    float denom = wself;
    float2 hv = *(const float2*)&h[(long long)d * ROW + j];
    float vx = wself * hv.x, vy = wself * hv.y;

    const int e1 = rowptr[d + 1];
    for (int e = rowptr[d]; e < e1; ++e) {
        int s = csr_src[e];
        float w = expf(lrelu(als[s * HL + hh] + ald_d));
        float2 hs = *(const float2*)&h[(long long)s * ROW + j];
        denom += w;
        vx += w * hs.x;
        vy += w * hs.y;
    }
    float inv = 1.f / denom;
    vx *= inv; vy *= inv;

    if (!MEAN) {
        vx += bias[j]; vy += bias[j + 1];
        vx = vx > 0.f ? vx : expf(vx) - 1.f;
        vy = vy > 0.f ? vy : expf(vy) - 1.f;
        *(float2*)&out[(long long)d * ROW + j] = make_float2(vx, vy);
    } else {
        // HL=2, C=64: lane l and l+32 hold the same output col for heads 0/1
        vx = 0.25f * vx + __shfl_xor(0.25f * vx, 32);
        vy = 0.25f * vy + __shfl_xor(0.25f * vy, 32);
        if (lane < 32) {
            float* op = &out[(long long)d * C + j];
            if (ACCUM) { vx += op[0] + bias[j]; vy += op[1] + bias[j + 1]; }
            *(float2*)op = make_float2(vx, vy);
        }
    }
}

extern "C" void kernel_launch(void* const* d_in, const int* in_sizes, int n_in,
                              void* d_out, int out_size, void* d_ws, size_t ws_size,
                              hipStream_t stream)
{
    const float* x      = (const float*)d_in[0];
    const void*  ei     = d_in[1];
    const float* W1     = (const float*)d_in[2];
    const float* a_src1 = (const float*)d_in[3];
    const float* a_dst1 = (const float*)d_in[4];
    const float* b1     = (const float*)d_in[5];
    const float* W2     = (const float*)d_in[6];
    const float* a_src2 = (const float*)d_in[7];
    const float* a_dst2 = (const float*)d_in[8];
    const float* b2     = (const float*)d_in[9];
    const float* W3     = (const float*)d_in[10];
    const float* a_src3 = (const float*)d_in[11];
    const float* a_dst3 = (const float*)d_in[12];
    const float* b3     = (const float*)d_in[13];

    const int N = in_sizes[0] / 128;
    const int E = in_sizes[1] / 2;

    char* w = (char*)d_ws;
    auto alloc = [&](size_t bytes) {
        char* p = w;
        w += (bytes + 255) & ~(size_t)255;
        return p;
    };
    int*   flag    = (int*)  alloc(256);
    int*   deg     = (int*)  alloc((size_t)N * 4);
    int*   rowptr  = (int*)  alloc((size_t)(N + 1) * 4);
    int*   cursor  = (int*)  alloc((size_t)N * 4);
    int*   csr_src = (int*)  alloc((size_t)E * 4);
    float* hbuf    = (float*)alloc((size_t)N * 128 * 4);
    float* xbuf    = (float*)alloc((size_t)N * 128 * 4);
    float* als     = (float*)alloc((size_t)N * 4 * 4);
    float* ald     = (float*)alloc((size_t)N * 4 * 4);
    if ((size_t)(w - (char*)d_ws) > ws_size) {
        fill_sentinel<<<(out_size + 255) / 256, 256, 0, stream>>>((float*)d_out, out_size);
        return;
    }

    const int gb = 256;
    const int mb = (N + 127) / 128;
    const int ab = (N * 64 + gb - 1) / gb;   // aggregate: one wave per node, 4 waves/block
    auto blocks = [&](long long tot) { return (int)((tot + gb - 1) / gb); };

    // ---------------- CSR build (per call; deterministic work) ----------------
    detect_idx64<<<1, 256, 0, stream>>>((const int*)ei, flag);
    hipMemsetAsync(deg, 0, (size_t)N * 4, stream);
    count_deg<<<blocks(E), gb, 0, stream>>>(ei, flag, deg, E);
    scan_deg<<<1, 1024, 0, stream>>>(deg, rowptr, cursor, N);
    fill_csr<<<blocks(E), gb, 0, stream>>>(ei, flag, cursor, csr_src, E);

    // ---------------- layer 1 ----------------
    gemm128<<<mb, gb, 0, stream>>>(x, W1, hbuf, N, 128, 0);
    node_att<32, 4><<<blocks(N * 4), gb, 0, stream>>>(hbuf, a_src1, a_dst1, als, ald, N);
    gat_aggregate<32, 4, false, false><<<ab, gb, 0, stream>>>(
        rowptr, csr_src, als, ald, hbuf, b1, xbuf, N);

    // ---------------- layer 2 ----------------
    gemm128<<<mb, gb, 0, stream>>>(xbuf, W2, hbuf, N, 128, 0);
    node_att<32, 4><<<blocks(N * 4), gb, 0, stream>>>(hbuf, a_src2, a_dst2, als, ald, N);
    gat_aggregate<32, 4, false, false><<<ab, gb, 0, stream>>>(
        rowptr, csr_src, als, ald, hbuf, b2, xbuf, N);

    // ---------------- layer 3: two head-pair chunks into d_out ----------------
    gemm128<<<mb, gb, 0, stream>>>(xbuf, W3, hbuf, N, 256, 0);
    node_att<64, 2><<<blocks(N * 2), gb, 0, stream>>>(hbuf, a_src3, a_dst3, als, ald, N);
    gat_aggregate<64, 2, true, false><<<ab, gb, 0, stream>>>(
        rowptr, csr_src, als, ald, hbuf, b3, (float*)d_out, N);

    gemm128<<<mb, gb, 0, stream>>>(xbuf, W3, hbuf, N, 256, 128);
    node_att<64, 2><<<blocks(N * 2), gb, 0, stream>>>(hbuf, a_src3 + 128, a_dst3 + 128, als, ald, N);
    gat_aggregate<64, 2, true, true><<<ab, gb, 0, stream>>>(
        rowptr, csr_src, als, ald, hbuf, b3, (float*)d_out, N);
}

// Round 5
// 1282.850 us; speedup vs baseline: 10.0101x; 1.2199x over previous
//
#include <hip/hip_runtime.h>

// GAT 3-layer forward. CSR-by-dst aggregation (atomic-free), bf16x2-split MFMA GEMM.
// Per layer: gemm_mfma (h = x@W via Ah*Wh+Ah*Wl+Al*Wh, f32 acc) -> node_att ->
// gat_aggregate: one WAVE per dst node, out = (sum w_e h[src] + w_self h[d]) / sum w;
// concat layers emit bf16 hi/lo (next GEMM's input), layer 3 head-means into d_out.
// segment_max dropped: cancels exactly in alpha = e/denom; logits are O(+-3) here.

#define NEG_SLOPE 0.2f

typedef __attribute__((ext_vector_type(8))) short short8v;   // 8 x bf16 bits
typedef __attribute__((ext_vector_type(4))) short short4v;
typedef __attribute__((ext_vector_type(2))) short short2v;
typedef __attribute__((ext_vector_type(4))) float f32x4;

__device__ __forceinline__ float lrelu(float v) { return v > 0.f ? v : NEG_SLOPE * v; }

__device__ __forceinline__ short bf16_rne(float f)
{
    unsigned u = __float_as_uint(f);
    unsigned r = (u + 0x7FFFu + ((u >> 16) & 1u)) >> 16;
    return (short)r;
}
__device__ __forceinline__ float bf16_to_f(short h)
{
    return __uint_as_float(((unsigned)(unsigned short)h) << 16);
}
// returns hi in .x, lo in .y (plain struct, no vector-element refs)
struct bf2 { short hi, lo; };
__device__ __forceinline__ bf2 split_bf16(float f)
{
    bf2 r;
    r.hi = bf16_rne(f);
    r.lo = bf16_rne(f - bf16_to_f(r.hi));
    return r;
}

// ---------------- diagnostics: workspace overflow sentinel ----------------
__global__ void fill_sentinel(float* __restrict__ out, int n)
{
    int i = blockIdx.x * blockDim.x + threadIdx.x;
    if (i < n) out[i] = 1e30f;
}

// ---------------- edge-index dtype detection (int64 vs int32) ----------------
__global__ void detect_idx64(const int* __restrict__ ei, int* __restrict__ flag)
{
    __shared__ int anynz;
    if (threadIdx.x == 0) anynz = 0;
    __syncthreads();
    int v = ei[2 * threadIdx.x + 1];   // high words if int64 (all values < 2^31)
    if (v != 0) atomicOr(&anynz, 1);
    __syncthreads();
    if (threadIdx.x == 0) flag[0] = (anynz == 0) ? 1 : 0;   // 1 => int64
}

// ---------------- CSR build ----------------
__global__ void count_deg(const void* __restrict__ ei, const int* __restrict__ flag,
                          int* __restrict__ deg, int E)
{
    int e = blockIdx.x * blockDim.x + threadIdx.x;
    if (e >= E) return;
    int d = flag[0] ? (int)((const long long*)ei)[E + e] : ((const int*)ei)[E + e];
    atomicAdd(&deg[d], 1);
}

// scanA: per-block (1024 elems) exclusive scan into rowptr, block totals to bsum
__global__ __launch_bounds__(256)
void scanA(const int* __restrict__ deg, int* __restrict__ rowptr,
           int* __restrict__ bsum, int N)
{
    __shared__ int part[256];
    const int t = threadIdx.x;
    const int base = blockIdx.x * 1024 + t * 4;
    int v[4];
    #pragma unroll
    for (int j = 0; j < 4; ++j) v[j] = (base + j < N) ? deg[base + j] : 0;
    int s = v[0] + v[1] + v[2] + v[3];
    part[t] = s;
    __syncthreads();
    #pragma unroll
    for (int off = 1; off < 256; off <<= 1) {
        int p = (t >= off) ? part[t - off] : 0;
        __syncthreads();
        part[t] += p;
        __syncthreads();
    }
    int run = (t == 0) ? 0 : part[t - 1];
    #pragma unroll
    for (int j = 0; j < 4; ++j) {
        if (base + j < N) rowptr[base + j] = run;
        run += v[j];
    }
    if (t == 255) bsum[blockIdx.x] = part[255];
}

// scanB: exclusive scan of block sums in place (nb <= 1024)
__global__ __launch_bounds__(1024)
void scanB(int* __restrict__ bsum, int nb)
{
    __shared__ int s[1024];
    int t = threadIdx.x;
    s[t] = (t < nb) ? bsum[t] : 0;
    __syncthreads();
    for (int off = 1; off < 1024; off <<= 1) {
        int p = (t >= off) ? s[t - off] : 0;
        __syncthreads();
        s[t] += p;
        __syncthreads();
    }
    if (t < nb) bsum[t] = (t == 0) ? 0 : s[t - 1];
}

// scanC: add block offsets; init cursor; set rowptr[N]=E
__global__ __launch_bounds__(256)
void scanC(int* __restrict__ rowptr, int* __restrict__ cursor,
           const int* __restrict__ bsum, int N, int E)
{
    const int base = blockIdx.x * 1024 + threadIdx.x * 4;
    const int off = bsum[blockIdx.x];
    #pragma unroll
    for (int j = 0; j < 4; ++j) {
        if (base + j < N) {
            int r = rowptr[base + j] + off;
            rowptr[base + j] = r;
            cursor[base + j] = r;
        }
    }
    if (blockIdx.x == 0 && threadIdx.x == 0) rowptr[N] = E;
}

__global__ void fill_csr(const void* __restrict__ ei, const int* __restrict__ flag,
                         int* __restrict__ cursor, int* __restrict__ csr_src, int E)
{
    int e = blockIdx.x * blockDim.x + threadIdx.x;
    if (e >= E) return;
    int s, d;
    if (flag[0]) { s = (int)((const long long*)ei)[e]; d = (int)((const long long*)ei)[E + e]; }
    else         { s = ((const int*)ei)[e];            d = ((const int*)ei)[E + e]; }
    int pos = atomicAdd(&cursor[d], 1);
    csr_src[pos] = s;
}

// ---------------- f32 -> bf16 hi/lo converts ----------------
__global__ void convert_hilo(const float* __restrict__ in, short* __restrict__ hi,
                             short* __restrict__ lo, long long n4)
{
    long long t = (long long)blockIdx.x * blockDim.x + threadIdx.x;
    if (t >= n4) return;
    float4 v = *(const float4*)&in[t * 4];
    bf2 a = split_bf16(v.x), b = split_bf16(v.y), c = split_bf16(v.z), d = split_bf16(v.w);
    short4v h, l;
    h.x = a.hi; h.y = b.hi; h.z = c.hi; h.w = d.hi;
    l.x = a.lo; l.y = b.lo; l.z = c.lo; l.w = d.lo;
    *(short4v*)&hi[t * 4] = h;
    *(short4v*)&lo[t * 4] = l;
}

// W chunk [128 k][128 n] (from W[k*ldw + wcol0 + n]) -> transposed Wt_hi/lo [n][k] bf16
__global__ __launch_bounds__(256)
void convert_wt(const float* __restrict__ W, short* __restrict__ wthi,
                short* __restrict__ wtlo, int ldw, int wcol0)
{
    int t = blockIdx.x * 256 + threadIdx.x;   // 16384 threads
    int k = t >> 7, n = t & 127;
    float v = W[(long long)k * ldw + wcol0 + n];
    bf2 r = split_bf16(v);
    wthi[n * 128 + k] = r.hi;
    wtlo[n * 128 + k] = r.lo;
}

// ---------------- MFMA GEMM: C[M][128] f32 = (Ahi+Alo) @ (Wthi+Wtlo)^T ----------------
// block = 256 thr = 4 waves; wave computes 16 rows x 128 cols; K = 128 (4 x k32).
// A frag: lane row = l&15, k = (l>>4)*8..+7 (16B global loads).
// B frag: Wt row n = nf*16 + (l&15), same k window (Wt is L2-hot, 64KB).
// D: row = (l>>4)*4 + r, col = l&15 (verified layout, m89/m91).
__global__ __launch_bounds__(256)
void gemm_mfma(const short* __restrict__ Ahi, const short* __restrict__ Alo,
               const short* __restrict__ Wthi, const short* __restrict__ Wtlo,
               float* __restrict__ C, int M)
{
    const int tid = threadIdx.x;
    const int wave = tid >> 6, lane = tid & 63;
    const int l15 = lane & 15, lk = lane >> 4;      // 0..3
    const int m0 = blockIdx.x * 64 + wave * 16;
    int mrow = m0 + l15;
    if (mrow >= M) mrow = M - 1;                     // clamp; stores guarded below

    f32x4 acc[8];
    #pragma unroll
    for (int i = 0; i < 8; ++i) acc[i] = (f32x4){0.f, 0.f, 0.f, 0.f};

    #pragma unroll
    for (int kt = 0; kt < 4; ++kt) {
        const int k = kt * 32 + lk * 8;
        short8v ah = *(const short8v*)&Ahi[(long long)mrow * 128 + k];
        short8v al = *(const short8v*)&Alo[(long long)mrow * 128 + k];
        #pragma unroll
        for (int nf = 0; nf < 8; ++nf) {
            short8v bh = *(const short8v*)&Wthi[(nf * 16 + l15) * 128 + k];
            short8v bl = *(const short8v*)&Wtlo[(nf * 16 + l15) * 128 + k];
            acc[nf] = __builtin_amdgcn_mfma_f32_16x16x32_bf16(ah, bh, acc[nf], 0, 0, 0);
            acc[nf] = __builtin_amdgcn_mfma_f32_16x16x32_bf16(ah, bl, acc[nf], 0, 0, 0);
            acc[nf] = __builtin_amdgcn_mfma_f32_16x16x32_bf16(al, bh, acc[nf], 0, 0, 0);
        }
    }

    #pragma unroll
    for (int r = 0; r < 4; ++r) {
        int gm = m0 + lk * 4 + r;
        if (gm >= M) continue;
        #pragma unroll
        for (int nf = 0; nf < 8; ++nf)
            C[(long long)gm * 128 + nf * 16 + l15] = acc[nf][r];
    }
}

// ---------------- per-node attention coefficients ----------------
template<int C, int HL>
__global__ void node_att(const float* __restrict__ h, const float* __restrict__ a_src,
                         const float* __restrict__ a_dst,
                         float* __restrict__ als, float* __restrict__ ald, int N)
{
    int t = blockIdx.x * blockDim.x + threadIdx.x;
    if (t >= N * HL) return;
    int n = t / HL, hh = t % HL;
    const float* hp = h + (long long)n * HL * C + hh * C;
    float s1 = 0.f, s2 = 0.f;
    #pragma unroll
    for (int c4 = 0; c4 < C / 4; ++c4) {
        float4 v  = *(const float4*)&hp[c4 * 4];
        float4 a1 = *(const float4*)&a_src[hh * C + c4 * 4];
        float4 a2 = *(const float4*)&a_dst[hh * C + c4 * 4];
        s1 += v.x * a1.x + v.y * a1.y + v.z * a1.z + v.w * a1.w;
        s2 += v.x * a2.x + v.y * a2.y + v.z * a2.z + v.w * a2.w;
    }
    als[t] = s1;
    ald[t] = s2;
}

// ---------------- fused aggregate: one wave per dst node ----------------
// ROW = HL*C = 128 floats; lane owns float2 at col j = lane*2.
// concat (MEAN=false): elu(vec/denom + bias) -> bf16 hi/lo (next GEMM input)
// mean   (MEAN=true) : out[d] (+)= 0.25 * headpair_sum(vec/denom) (+ bias if ACCUM)
template<int C, int HL, bool MEAN, bool ACCUM>
__global__ __launch_bounds__(256)
void gat_aggregate(const int* __restrict__ rowptr, const int* __restrict__ csr_src,
                   const float* __restrict__ als, const float* __restrict__ ald,
                   const float* __restrict__ h, const float* __restrict__ bias,
                   float* __restrict__ out, short* __restrict__ ohi,
                   short* __restrict__ olo, int N)
{
    constexpr int ROW = HL * C;   // 128
    const int d = (blockIdx.x * blockDim.x + threadIdx.x) >> 6;
    const int lane = threadIdx.x & 63;
    if (d >= N) return;
    const int j = lane * 2;
    const int hh = j / C;

    const float ald_d = ald[d * HL + hh];
    const float wself = expf(lrelu(als[d * HL + hh] + ald_d));
    float denom = wself;
    float2 hv = *(const float2*)&h[(long long)d * ROW + j];
    float vx = wself * hv.x, vy = wself * hv.y;

    const int e1 = rowptr[d + 1];
    for (int e = rowptr[d]; e < e1; ++e) {
        int s = csr_src[e];
        float w = expf(lrelu(als[s * HL + hh] + ald_d));
        float2 hs = *(const float2*)&h[(long long)s * ROW + j];
        denom += w;
        vx += w * hs.x;
        vy += w * hs.y;
    }
    float inv = 1.f / denom;
    vx *= inv; vy *= inv;

    if (!MEAN) {
        vx += bias[j]; vy += bias[j + 1];
        vx = vx > 0.f ? vx : expf(vx) - 1.f;
        vy = vy > 0.f ? vy : expf(vy) - 1.f;
        bf2 rx = split_bf16(vx), ry = split_bf16(vy);
        short2v hi2, lo2;
        hi2.x = rx.hi; hi2.y = ry.hi;
        lo2.x = rx.lo; lo2.y = ry.lo;
        *(short2v*)&ohi[(long long)d * ROW + j] = hi2;
        *(short2v*)&olo[(long long)d * ROW + j] = lo2;
    } else {
        // HL=2, C=64: lane l and l+32 hold the same output col for heads 0/1
        vx = 0.25f * vx + __shfl_xor(0.25f * vx, 32);
        vy = 0.25f * vy + __shfl_xor(0.25f * vy, 32);
        if (lane < 32) {
            float* op = &out[(long long)d * C + j];
            if (ACCUM) { vx += op[0] + bias[j]; vy += op[1] + bias[j + 1]; }
            *(float2*)op = make_float2(vx, vy);
        }
    }
}

extern "C" void kernel_launch(void* const* d_in, const int* in_sizes, int n_in,
                              void* d_out, int out_size, void* d_ws, size_t ws_size,
                              hipStream_t stream)
{
    const float* x      = (const float*)d_in[0];
    const void*  ei     = d_in[1];
    const float* W1     = (const float*)d_in[2];
    const float* a_src1 = (const float*)d_in[3];
    const float* a_dst1 = (const float*)d_in[4];
    const float* b1     = (const float*)d_in[5];
    const float* W2     = (const float*)d_in[6];
    const float* a_src2 = (const float*)d_in[7];
    const float* a_dst2 = (const float*)d_in[8];
    const float* b2     = (const float*)d_in[9];
    const float* W3     = (const float*)d_in[10];
    const float* a_src3 = (const float*)d_in[11];
    const float* a_dst3 = (const float*)d_in[12];
    const float* b3     = (const float*)d_in[13];

    const int N = in_sizes[0] / 128;
    const int E = in_sizes[1] / 2;

    char* w = (char*)d_ws;
    auto alloc = [&](size_t bytes) {
        char* p = w;
        w += (bytes + 255) & ~(size_t)255;
        return p;
    };
    int*   flag    = (int*)  alloc(256);
    int*   deg     = (int*)  alloc((size_t)N * 4);
    int*   rowptr  = (int*)  alloc((size_t)(N + 1) * 4);
    int*   cursor  = (int*)  alloc((size_t)N * 4);
    int*   bsum    = (int*)  alloc(1024 * 4);
    int*   csr_src = (int*)  alloc((size_t)E * 4);
    float* hbuf    = (float*)alloc((size_t)N * 128 * 4);
    short* xhi     = (short*)alloc((size_t)N * 128 * 2);
    short* xlo     = (short*)alloc((size_t)N * 128 * 2);
    float* als     = (float*)alloc((size_t)N * 4 * 4);
    float* ald     = (float*)alloc((size_t)N * 4 * 4);
    short* wthi    = (short*)alloc(128 * 128 * 2);
    short* wtlo    = (short*)alloc(128 * 128 * 2);
    if ((size_t)(w - (char*)d_ws) > ws_size) {
        fill_sentinel<<<(out_size + 255) / 256, 256, 0, stream>>>((float*)d_out, out_size);
        return;
    }

    const int gb = 256;
    const int nb1024 = (N + 1023) / 1024;
    const int mb = (N + 63) / 64;                  // gemm blocks (64 rows each)
    const int ab = (N * 64 + gb - 1) / gb;         // aggregate: 1 wave/node
    auto blocks = [&](long long tot) { return (int)((tot + gb - 1) / gb); };

    // ---------------- CSR build ----------------
    detect_idx64<<<1, 256, 0, stream>>>((const int*)ei, flag);
    (void)hipMemsetAsync(deg, 0, (size_t)N * 4, stream);
    count_deg<<<blocks(E), gb, 0, stream>>>(ei, flag, deg, E);
    scanA<<<nb1024, gb, 0, stream>>>(deg, rowptr, bsum, N);
    scanB<<<1, 1024, 0, stream>>>(bsum, nb1024);
    scanC<<<nb1024, gb, 0, stream>>>(rowptr, cursor, bsum, N, E);
    fill_csr<<<blocks(E), gb, 0, stream>>>(ei, flag, cursor, csr_src, E);

    // layer-1 input -> bf16 hi/lo
    convert_hilo<<<blocks((long long)N * 32), gb, 0, stream>>>(x, xhi, xlo, (long long)N * 32);

    // ---------------- layer 1 ----------------
    convert_wt<<<64, gb, 0, stream>>>(W1, wthi, wtlo, 128, 0);
    gemm_mfma<<<mb, gb, 0, stream>>>(xhi, xlo, wthi, wtlo, hbuf, N);
    node_att<32, 4><<<blocks(N * 4), gb, 0, stream>>>(hbuf, a_src1, a_dst1, als, ald, N);
    gat_aggregate<32, 4, false, false><<<ab, gb, 0, stream>>>(
        rowptr, csr_src, als, ald, hbuf, b1, nullptr, xhi, xlo, N);

    // ---------------- layer 2 ----------------
    convert_wt<<<64, gb, 0, stream>>>(W2, wthi, wtlo, 128, 0);
    gemm_mfma<<<mb, gb, 0, stream>>>(xhi, xlo, wthi, wtlo, hbuf, N);
    node_att<32, 4><<<blocks(N * 4), gb, 0, stream>>>(hbuf, a_src2, a_dst2, als, ald, N);
    gat_aggregate<32, 4, false, false><<<ab, gb, 0, stream>>>(
        rowptr, csr_src, als, ald, hbuf, b2, nullptr, xhi, xlo, N);

    // ---------------- layer 3: two head-pair chunks into d_out ----------------
    convert_wt<<<64, gb, 0, stream>>>(W3, wthi, wtlo, 256, 0);
    gemm_mfma<<<mb, gb, 0, stream>>>(xhi, xlo, wthi, wtlo, hbuf, N);
    node_att<64, 2><<<blocks(N * 2), gb, 0, stream>>>(hbuf, a_src3, a_dst3, als, ald, N);
    gat_aggregate<64, 2, true, false><<<ab, gb, 0, stream>>>(
        rowptr, csr_src, als, ald, hbuf, b3, (float*)d_out, nullptr, nullptr, N);

    convert_wt<<<64, gb, 0, stream>>>(W3, wthi, wtlo, 256, 128);
    gemm_mfma<<<mb, gb, 0, stream>>>(xhi, xlo, wthi, wtlo, hbuf, N);
    node_att<64, 2><<<blocks(N * 2), gb, 0, stream>>>(hbuf, a_src3 + 128, a_dst3 + 128, als, ald, N);
    gat_aggregate<64, 2, true, true><<<ab, gb, 0, stream>>>(
        rowptr, csr_src, als, ald, hbuf, b3, (float*)d_out, nullptr, nullptr, N);
}

// Round 6
// 1033.788 us; speedup vs baseline: 12.4217x; 1.2409x over previous
//
#include <hip/hip_runtime.h>

// GAT 3-layer forward. CSR-by-dst aggregation (atomic-free, batch-8 ILP gather),
// bf16x2-split MFMA GEMM with fused node_att epilogue.
// Per layer: gemm_mfma (h = x@W, + als/ald row-dots in epilogue) -> gat_aggregate:
//   one WAVE per dst node, out = (sum w_e h[src] + w_self h[d]) / sum w;
//   concat layers emit bf16 hi/lo (next GEMM's input), layer 3 head-means into d_out.
// segment_max dropped: cancels exactly in alpha = e/denom; logits are O(+-3) here.

#define NEG_SLOPE 0.2f

typedef __attribute__((ext_vector_type(8))) short short8v;   // 8 x bf16 bits
typedef __attribute__((ext_vector_type(4))) short short4v;
typedef __attribute__((ext_vector_type(2))) short short2v;
typedef __attribute__((ext_vector_type(4))) float f32x4;

__device__ __forceinline__ float lrelu(float v) { return v > 0.f ? v : NEG_SLOPE * v; }

__device__ __forceinline__ short bf16_rne(float f)
{
    unsigned u = __float_as_uint(f);
    unsigned r = (u + 0x7FFFu + ((u >> 16) & 1u)) >> 16;
    return (short)r;
}
__device__ __forceinline__ float bf16_to_f(short h)
{
    return __uint_as_float(((unsigned)(unsigned short)h) << 16);
}
struct bf2 { short hi, lo; };
__device__ __forceinline__ bf2 split_bf16(float f)
{
    bf2 r;
    r.hi = bf16_rne(f);
    r.lo = bf16_rne(f - bf16_to_f(r.hi));
    return r;
}

// ---------------- diagnostics: workspace overflow sentinel ----------------
__global__ void fill_sentinel(float* __restrict__ out, int n)
{
    int i = blockIdx.x * blockDim.x + threadIdx.x;
    if (i < n) out[i] = 1e30f;
}

// ---------------- edge-index dtype detection (int64 vs int32) ----------------
__global__ void detect_idx64(const int* __restrict__ ei, int* __restrict__ flag)
{
    __shared__ int anynz;
    if (threadIdx.x == 0) anynz = 0;
    __syncthreads();
    int v = ei[2 * threadIdx.x + 1];   // high words if int64 (all values < 2^31)
    if (v != 0) atomicOr(&anynz, 1);
    __syncthreads();
    if (threadIdx.x == 0) flag[0] = (anynz == 0) ? 1 : 0;   // 1 => int64
}

// ---------------- CSR build ----------------
__global__ void count_deg(const void* __restrict__ ei, const int* __restrict__ flag,
                          int* __restrict__ deg, int E)
{
    int e = blockIdx.x * blockDim.x + threadIdx.x;
    if (e >= E) return;
    int d = flag[0] ? (int)((const long long*)ei)[E + e] : ((const int*)ei)[E + e];
    atomicAdd(&deg[d], 1);
}

__global__ __launch_bounds__(256)
void scanA(const int* __restrict__ deg, int* __restrict__ rowptr,
           int* __restrict__ bsum, int N)
{
    __shared__ int part[256];
    const int t = threadIdx.x;
    const int base = blockIdx.x * 1024 + t * 4;
    int v[4];
    #pragma unroll
    for (int j = 0; j < 4; ++j) v[j] = (base + j < N) ? deg[base + j] : 0;
    int s = v[0] + v[1] + v[2] + v[3];
    part[t] = s;
    __syncthreads();
    #pragma unroll
    for (int off = 1; off < 256; off <<= 1) {
        int p = (t >= off) ? part[t - off] : 0;
        __syncthreads();
        part[t] += p;
        __syncthreads();
    }
    int run = (t == 0) ? 0 : part[t - 1];
    #pragma unroll
    for (int j = 0; j < 4; ++j) {
        if (base + j < N) rowptr[base + j] = run;
        run += v[j];
    }
    if (t == 255) bsum[blockIdx.x] = part[255];
}

__global__ __launch_bounds__(1024)
void scanB(int* __restrict__ bsum, int nb)
{
    __shared__ int s[1024];
    int t = threadIdx.x;
    s[t] = (t < nb) ? bsum[t] : 0;
    __syncthreads();
    for (int off = 1; off < 1024; off <<= 1) {
        int p = (t >= off) ? s[t - off] : 0;
        __syncthreads();
        s[t] += p;
        __syncthreads();
    }
    if (t < nb) bsum[t] = (t == 0) ? 0 : s[t - 1];
}

__global__ __launch_bounds__(256)
void scanC(int* __restrict__ rowptr, int* __restrict__ cursor,
           const int* __restrict__ bsum, int N, int E)
{
    const int base = blockIdx.x * 1024 + threadIdx.x * 4;
    const int off = bsum[blockIdx.x];
    #pragma unroll
    for (int j = 0; j < 4; ++j) {
        if (base + j < N) {
            int r = rowptr[base + j] + off;
            rowptr[base + j] = r;
            cursor[base + j] = r;
        }
    }
    if (blockIdx.x == 0 && threadIdx.x == 0) rowptr[N] = E;
}

__global__ void fill_csr(const void* __restrict__ ei, const int* __restrict__ flag,
                         int* __restrict__ cursor, int* __restrict__ csr_src, int E)
{
    int e = blockIdx.x * blockDim.x + threadIdx.x;
    if (e >= E) return;
    int s, d;
    if (flag[0]) { s = (int)((const long long*)ei)[e]; d = (int)((const long long*)ei)[E + e]; }
    else         { s = ((const int*)ei)[e];            d = ((const int*)ei)[E + e]; }
    int pos = atomicAdd(&cursor[d], 1);
    csr_src[pos] = s;
}

// ---------------- f32 -> bf16 hi/lo converts ----------------
__global__ void convert_hilo(const float* __restrict__ in, short* __restrict__ hi,
                             short* __restrict__ lo, long long n4)
{
    long long t = (long long)blockIdx.x * blockDim.x + threadIdx.x;
    if (t >= n4) return;
    float4 v = *(const float4*)&in[t * 4];
    bf2 a = split_bf16(v.x), b = split_bf16(v.y), c = split_bf16(v.z), d = split_bf16(v.w);
    short4v h, l;
    h.x = a.hi; h.y = b.hi; h.z = c.hi; h.w = d.hi;
    l.x = a.lo; l.y = b.lo; l.z = c.lo; l.w = d.lo;
    *(short4v*)&hi[t * 4] = h;
    *(short4v*)&lo[t * 4] = l;
}

// W chunk [128 k][128 n] -> transposed Wt_hi/lo [n][k] bf16
__global__ __launch_bounds__(256)
void convert_wt(const float* __restrict__ W, short* __restrict__ wthi,
                short* __restrict__ wtlo, int ldw, int wcol0)
{
    int t = blockIdx.x * 256 + threadIdx.x;   // 16384 threads
    int k = t >> 7, n = t & 127;
    float v = W[(long long)k * ldw + wcol0 + n];
    bf2 r = split_bf16(v);
    wthi[n * 128 + k] = r.hi;
    wtlo[n * 128 + k] = r.lo;
}

// ---------------- MFMA GEMM + fused node_att epilogue ----------------
// C[M][128] f32 = (Ahi+Alo) @ (Wthi+Wtlo)^T; block = 4 waves, wave = 16 rows x 128 cols.
// A frag: lane row = l&15, k = (l>>4)*8..+7. B frag: Wt row n = nf*16 + (l&15).
// D: row = (l>>4)*4 + r, col = l&15 (verified layout, m89/m91).
// Epilogue: als/ald[row,h] = <C_row_head, a_flat> via in-register dot + 16-lane shfl tree.
// HPC = heads per 128-col chunk (4 for C=32, 2 for C=64).
template<int HPC>
__global__ __launch_bounds__(256)
void gemm_mfma(const short* __restrict__ Ahi, const short* __restrict__ Alo,
               const short* __restrict__ Wthi, const short* __restrict__ Wtlo,
               float* __restrict__ C, const float* __restrict__ aS,
               const float* __restrict__ aD, float* __restrict__ als,
               float* __restrict__ ald, int M)
{
    const int tid = threadIdx.x;
    const int wave = tid >> 6, lane = tid & 63;
    const int l15 = lane & 15, lk = lane >> 4;      // 0..3
    const int m0 = blockIdx.x * 64 + wave * 16;
    int mrow = m0 + l15;
    if (mrow >= M) mrow = M - 1;                     // clamp; stores guarded below

    f32x4 acc[8];
    #pragma unroll
    for (int i = 0; i < 8; ++i) acc[i] = (f32x4){0.f, 0.f, 0.f, 0.f};

    #pragma unroll
    for (int kt = 0; kt < 4; ++kt) {
        const int k = kt * 32 + lk * 8;
        short8v ah = *(const short8v*)&Ahi[(long long)mrow * 128 + k];
        short8v al = *(const short8v*)&Alo[(long long)mrow * 128 + k];
        #pragma unroll
        for (int nf = 0; nf < 8; ++nf) {
            short8v bh = *(const short8v*)&Wthi[(nf * 16 + l15) * 128 + k];
            short8v bl = *(const short8v*)&Wtlo[(nf * 16 + l15) * 128 + k];
            acc[nf] = __builtin_amdgcn_mfma_f32_16x16x32_bf16(ah, bh, acc[nf], 0, 0, 0);
            acc[nf] = __builtin_amdgcn_mfma_f32_16x16x32_bf16(ah, bl, acc[nf], 0, 0, 0);
            acc[nf] = __builtin_amdgcn_mfma_f32_16x16x32_bf16(al, bh, acc[nf], 0, 0, 0);
        }
    }

    // store C
    #pragma unroll
    for (int r = 0; r < 4; ++r) {
        int gm = m0 + lk * 4 + r;
        if (gm >= M) continue;
        #pragma unroll
        for (int nf = 0; nf < 8; ++nf)
            C[(long long)gm * 128 + nf * 16 + l15] = acc[nf][r];
    }

    // fused node_att: col = nf*16 + l15, head = col / (128/HPC) = nf / (8/HPC)
    float asv[8], adv[8];
    #pragma unroll
    for (int nf = 0; nf < 8; ++nf) {
        asv[nf] = aS[nf * 16 + l15];
        adv[nf] = aD[nf * 16 + l15];
    }
    constexpr int NFH = 8 / HPC;   // acc regs per head
    #pragma unroll
    for (int r = 0; r < 4; ++r) {
        #pragma unroll
        for (int h = 0; h < HPC; ++h) {
            float ps = 0.f, pd = 0.f;
            #pragma unroll
            for (int q = 0; q < NFH; ++q) {
                int nf = h * NFH + q;
                ps += acc[nf][r] * asv[nf];
                pd += acc[nf][r] * adv[nf];
            }
            #pragma unroll
            for (int m = 1; m < 16; m <<= 1) {
                ps += __shfl_xor(ps, m);
                pd += __shfl_xor(pd, m);
            }
            if (l15 == 0) {
                int gm = m0 + lk * 4 + r;
                if (gm < M) {
                    als[gm * HPC + h] = ps;
                    ald[gm * HPC + h] = pd;
                }
            }
        }
    }
}

// ---------------- fused aggregate: one wave per dst node, batch-8 ILP ----------------
// ROW = HL*C = 128 floats; lane owns float2 at col j = lane*2.
// concat (MEAN=false): elu(vec/denom + bias) -> bf16 hi/lo (next GEMM input)
// mean   (MEAN=true) : out[d] (+)= 0.25 * headpair_sum(vec/denom) (+ bias if ACCUM)
template<int C, int HL, bool MEAN, bool ACCUM>
__global__ __launch_bounds__(256)
void gat_aggregate(const int* __restrict__ rowptr, const int* __restrict__ csr_src,
                   const float* __restrict__ als, const float* __restrict__ ald,
                   const float* __restrict__ h, const float* __restrict__ bias,
                   float* __restrict__ out, short* __restrict__ ohi,
                   short* __restrict__ olo, int N)
{
    constexpr int ROW = HL * C;   // 128
    constexpr int B = 8;          // ILP batch
    const int d = (blockIdx.x * blockDim.x + threadIdx.x) >> 6;
    const int lane = threadIdx.x & 63;
    if (d >= N) return;
    const int j = lane * 2;
    const int hh = j / C;

    const float ald_d = ald[d * HL + hh];
    const float wself = expf(lrelu(als[d * HL + hh] + ald_d));
    float denom = wself;
    float2 hv = *(const float2*)&h[(long long)d * ROW + j];
    float vx = wself * hv.x, vy = wself * hv.y;

    const int e0 = rowptr[d], e1 = rowptr[d + 1];
    for (int base = e0; base < e1; base += B) {
        int   sv[B];
        float av[B];
        float2 hb[B];
        #pragma unroll
        for (int i = 0; i < B; ++i) {
            int ee = base + i;
            sv[i] = csr_src[ee < e1 ? ee : e1 - 1];   // clamp; masked below
        }
        #pragma unroll
        for (int i = 0; i < B; ++i) av[i] = als[sv[i] * HL + hh];
        #pragma unroll
        for (int i = 0; i < B; ++i) hb[i] = *(const float2*)&h[(long long)sv[i] * ROW + j];
        #pragma unroll
        for (int i = 0; i < B; ++i) {
            float wv = expf(lrelu(av[i] + ald_d));
            wv = (base + i < e1) ? wv : 0.f;
            denom += wv;
            vx += wv * hb[i].x;
            vy += wv * hb[i].y;
        }
    }
    float inv = 1.f / denom;
    vx *= inv; vy *= inv;

    if (!MEAN) {
        vx += bias[j]; vy += bias[j + 1];
        vx = vx > 0.f ? vx : expf(vx) - 1.f;
        vy = vy > 0.f ? vy : expf(vy) - 1.f;
        bf2 rx = split_bf16(vx), ry = split_bf16(vy);
        short2v hi2, lo2;
        hi2.x = rx.hi; hi2.y = ry.hi;
        lo2.x = rx.lo; lo2.y = ry.lo;
        *(short2v*)&ohi[(long long)d * ROW + j] = hi2;
        *(short2v*)&olo[(long long)d * ROW + j] = lo2;
    } else {
        // HL=2, C=64: lane l and l+32 hold the same output col for heads 0/1
        vx = 0.25f * vx + __shfl_xor(0.25f * vx, 32);
        vy = 0.25f * vy + __shfl_xor(0.25f * vy, 32);
        if (lane < 32) {
            float* op = &out[(long long)d * C + j];
            if (ACCUM) { vx += op[0] + bias[j]; vy += op[1] + bias[j + 1]; }
            *(float2*)op = make_float2(vx, vy);
        }
    }
}

extern "C" void kernel_launch(void* const* d_in, const int* in_sizes, int n_in,
                              void* d_out, int out_size, void* d_ws, size_t ws_size,
                              hipStream_t stream)
{
    const float* x      = (const float*)d_in[0];
    const void*  ei     = d_in[1];
    const float* W1     = (const float*)d_in[2];
    const float* a_src1 = (const float*)d_in[3];
    const float* a_dst1 = (const float*)d_in[4];
    const float* b1     = (const float*)d_in[5];
    const float* W2     = (const float*)d_in[6];
    const float* a_src2 = (const float*)d_in[7];
    const float* a_dst2 = (const float*)d_in[8];
    const float* b2     = (const float*)d_in[9];
    const float* W3     = (const float*)d_in[10];
    const float* a_src3 = (const float*)d_in[11];
    const float* a_dst3 = (const float*)d_in[12];
    const float* b3     = (const float*)d_in[13];

    const int N = in_sizes[0] / 128;
    const int E = in_sizes[1] / 2;

    char* w = (char*)d_ws;
    auto alloc = [&](size_t bytes) {
        char* p = w;
        w += (bytes + 255) & ~(size_t)255;
        return p;
    };
    int*   flag    = (int*)  alloc(256);
    int*   deg     = (int*)  alloc((size_t)N * 4);
    int*   rowptr  = (int*)  alloc((size_t)(N + 1) * 4);
    int*   cursor  = (int*)  alloc((size_t)N * 4);
    int*   bsum    = (int*)  alloc(1024 * 4);
    int*   csr_src = (int*)  alloc((size_t)E * 4);
    float* hbuf    = (float*)alloc((size_t)N * 128 * 4);
    short* xhi     = (short*)alloc((size_t)N * 128 * 2);
    short* xlo     = (short*)alloc((size_t)N * 128 * 2);
    float* als     = (float*)alloc((size_t)N * 4 * 4);
    float* ald     = (float*)alloc((size_t)N * 4 * 4);
    short* wthi    = (short*)alloc(128 * 128 * 2);
    short* wtlo    = (short*)alloc(128 * 128 * 2);
    if ((size_t)(w - (char*)d_ws) > ws_size) {
        fill_sentinel<<<(out_size + 255) / 256, 256, 0, stream>>>((float*)d_out, out_size);
        return;
    }

    const int gb = 256;
    const int nb1024 = (N + 1023) / 1024;
    const int mb = (N + 63) / 64;                  // gemm blocks (64 rows each)
    const int ab = (N * 64 + gb - 1) / gb;         // aggregate: 1 wave/node
    auto blocks = [&](long long tot) { return (int)((tot + gb - 1) / gb); };

    // ---------------- CSR build ----------------
    detect_idx64<<<1, 256, 0, stream>>>((const int*)ei, flag);
    (void)hipMemsetAsync(deg, 0, (size_t)N * 4, stream);
    count_deg<<<blocks(E), gb, 0, stream>>>(ei, flag, deg, E);
    scanA<<<nb1024, gb, 0, stream>>>(deg, rowptr, bsum, N);
    scanB<<<1, 1024, 0, stream>>>(bsum, nb1024);
    scanC<<<nb1024, gb, 0, stream>>>(rowptr, cursor, bsum, N, E);
    fill_csr<<<blocks(E), gb, 0, stream>>>(ei, flag, cursor, csr_src, E);

    // layer-1 input -> bf16 hi/lo
    convert_hilo<<<blocks((long long)N * 32), gb, 0, stream>>>(x, xhi, xlo, (long long)N * 32);

    // ---------------- layer 1 ----------------
    convert_wt<<<64, gb, 0, stream>>>(W1, wthi, wtlo, 128, 0);
    gemm_mfma<4><<<mb, gb, 0, stream>>>(xhi, xlo, wthi, wtlo, hbuf, a_src1, a_dst1, als, ald, N);
    gat_aggregate<32, 4, false, false><<<ab, gb, 0, stream>>>(
        rowptr, csr_src, als, ald, hbuf, b1, nullptr, xhi, xlo, N);

    // ---------------- layer 2 ----------------
    convert_wt<<<64, gb, 0, stream>>>(W2, wthi, wtlo, 128, 0);
    gemm_mfma<4><<<mb, gb, 0, stream>>>(xhi, xlo, wthi, wtlo, hbuf, a_src2, a_dst2, als, ald, N);
    gat_aggregate<32, 4, false, false><<<ab, gb, 0, stream>>>(
        rowptr, csr_src, als, ald, hbuf, b2, nullptr, xhi, xlo, N);

    // ---------------- layer 3: two head-pair chunks into d_out ----------------
    convert_wt<<<64, gb, 0, stream>>>(W3, wthi, wtlo, 256, 0);
    gemm_mfma<2><<<mb, gb, 0, stream>>>(xhi, xlo, wthi, wtlo, hbuf, a_src3, a_dst3, als, ald, N);
    gat_aggregate<64, 2, true, false><<<ab, gb, 0, stream>>>(
        rowptr, csr_src, als, ald, hbuf, b3, (float*)d_out, nullptr, nullptr, N);

    convert_wt<<<64, gb, 0, stream>>>(W3, wthi, wtlo, 256, 128);
    gemm_mfma<2><<<mb, gb, 0, stream>>>(xhi, xlo, wthi, wtlo, hbuf,
                                        a_src3 + 128, a_dst3 + 128, als, ald, N);
    gat_aggregate<64, 2, true, true><<<ab, gb, 0, stream>>>(
        rowptr, csr_src, als, ald, hbuf, b3, (float*)d_out, nullptr, nullptr, N);
}

// Round 7
// 937.913 us; speedup vs baseline: 13.6915x; 1.1022x over previous
//
#include <hip/hip_runtime.h>

// GAT 3-layer forward. CSR-by-dst aggregation (atomic-free, batch-8 ILP gather of
// fp16 rows), fp16x2-split MFMA GEMM with fused node_att epilogue.
// Per layer: gemm_mfma (h = x@W, writes f32 h + fp16 h, + als/ald row-dots) ->
// gat_aggregate: one WAVE per dst node, out = (sum w_e h16[src] + w_self h32[d]) / sum w;
// concat layers emit fp16 hi/lo (next GEMM's input), layer 3 head-means into d_out.
// segment_max dropped: cancels exactly in alpha = e/denom; logits are O(+-3) here.

#define NEG_SLOPE 0.2f

typedef __attribute__((ext_vector_type(8))) _Float16 half8v;
typedef __attribute__((ext_vector_type(2))) _Float16 half2v;
typedef __attribute__((ext_vector_type(4))) float f32x4;

__device__ __forceinline__ float lrelu(float v) { return v > 0.f ? v : NEG_SLOPE * v; }

struct hf2 { _Float16 hi, lo; };
__device__ __forceinline__ hf2 split_f16(float f)
{
    hf2 r;
    r.hi = (_Float16)f;
    r.lo = (_Float16)(f - (float)r.hi);
    return r;
}

// ---------------- diagnostics: workspace overflow sentinel ----------------
__global__ void fill_sentinel(float* __restrict__ out, int n)
{
    int i = blockIdx.x * blockDim.x + threadIdx.x;
    if (i < n) out[i] = 1e30f;
}

// ---------------- edge-index dtype detection (int64 vs int32) ----------------
__global__ void detect_idx64(const int* __restrict__ ei, int* __restrict__ flag)
{
    __shared__ int anynz;
    if (threadIdx.x == 0) anynz = 0;
    __syncthreads();
    int v = ei[2 * threadIdx.x + 1];   // high words if int64 (all values < 2^31)
    if (v != 0) atomicOr(&anynz, 1);
    __syncthreads();
    if (threadIdx.x == 0) flag[0] = (anynz == 0) ? 1 : 0;   // 1 => int64
}

// ---------------- CSR build ----------------
__global__ void count_deg(const void* __restrict__ ei, const int* __restrict__ flag,
                          int* __restrict__ deg, int E)
{
    int e = blockIdx.x * blockDim.x + threadIdx.x;
    if (e >= E) return;
    int d = flag[0] ? (int)((const long long*)ei)[E + e] : ((const int*)ei)[E + e];
    atomicAdd(&deg[d], 1);
}

__global__ __launch_bounds__(256)
void scanA(const int* __restrict__ deg, int* __restrict__ rowptr,
           int* __restrict__ bsum, int N)
{
    __shared__ int part[256];
    const int t = threadIdx.x;
    const int base = blockIdx.x * 1024 + t * 4;
    int v[4];
    #pragma unroll
    for (int j = 0; j < 4; ++j) v[j] = (base + j < N) ? deg[base + j] : 0;
    int s = v[0] + v[1] + v[2] + v[3];
    part[t] = s;
    __syncthreads();
    #pragma unroll
    for (int off = 1; off < 256; off <<= 1) {
        int p = (t >= off) ? part[t - off] : 0;
        __syncthreads();
        part[t] += p;
        __syncthreads();
    }
    int run = (t == 0) ? 0 : part[t - 1];
    #pragma unroll
    for (int j = 0; j < 4; ++j) {
        if (base + j < N) rowptr[base + j] = run;
        run += v[j];
    }
    if (t == 255) bsum[blockIdx.x] = part[255];
}

__global__ __launch_bounds__(1024)
void scanB(int* __restrict__ bsum, int nb)
{
    __shared__ int s[1024];
    int t = threadIdx.x;
    s[t] = (t < nb) ? bsum[t] : 0;
    __syncthreads();
    for (int off = 1; off < 1024; off <<= 1) {
        int p = (t >= off) ? s[t - off] : 0;
        __syncthreads();
        s[t] += p;
        __syncthreads();
    }
    if (t < nb) bsum[t] = (t == 0) ? 0 : s[t - 1];
}

__global__ __launch_bounds__(256)
void scanC(int* __restrict__ rowptr, int* __restrict__ cursor,
           const int* __restrict__ bsum, int N, int E)
{
    const int base = blockIdx.x * 1024 + threadIdx.x * 4;
    const int off = bsum[blockIdx.x];
    #pragma unroll
    for (int j = 0; j < 4; ++j) {
        if (base + j < N) {
            int r = rowptr[base + j] + off;
            rowptr[base + j] = r;
            cursor[base + j] = r;
        }
    }
    if (blockIdx.x == 0 && threadIdx.x == 0) rowptr[N] = E;
}

__global__ void fill_csr(const void* __restrict__ ei, const int* __restrict__ flag,
                         int* __restrict__ cursor, int* __restrict__ csr_src, int E)
{
    int e = blockIdx.x * blockDim.x + threadIdx.x;
    if (e >= E) return;
    int s, d;
    if (flag[0]) { s = (int)((const long long*)ei)[e]; d = (int)((const long long*)ei)[E + e]; }
    else         { s = ((const int*)ei)[e];            d = ((const int*)ei)[E + e]; }
    int pos = atomicAdd(&cursor[d], 1);
    csr_src[pos] = s;
}

// ---------------- f32 -> fp16 hi/lo converts ----------------
__global__ void convert_hilo(const float* __restrict__ in, _Float16* __restrict__ hi,
                             _Float16* __restrict__ lo, long long n4)
{
    long long t = (long long)blockIdx.x * blockDim.x + threadIdx.x;
    if (t >= n4) return;
    float4 v = *(const float4*)&in[t * 4];
    hf2 a = split_f16(v.x), b = split_f16(v.y), c = split_f16(v.z), d = split_f16(v.w);
    __attribute__((ext_vector_type(4))) _Float16 h, l;
    h.x = a.hi; h.y = b.hi; h.z = c.hi; h.w = d.hi;
    l.x = a.lo; l.y = b.lo; l.z = c.lo; l.w = d.lo;
    *(decltype(h)*)&hi[t * 4] = h;
    *(decltype(l)*)&lo[t * 4] = l;
}

// W chunk [128 k][128 n] -> transposed Wt_hi/lo [n][k] fp16
__global__ __launch_bounds__(256)
void convert_wt(const float* __restrict__ W, _Float16* __restrict__ wthi,
                _Float16* __restrict__ wtlo, int ldw, int wcol0)
{
    int t = blockIdx.x * 256 + threadIdx.x;   // 16384 threads
    int k = t >> 7, n = t & 127;
    float v = W[(long long)k * ldw + wcol0 + n];
    hf2 r = split_f16(v);
    wthi[n * 128 + k] = r.hi;
    wtlo[n * 128 + k] = r.lo;
}

// ---------------- MFMA GEMM + fused node_att epilogue ----------------
// C[M][128] f32 = (Ahi+Alo) @ (Wthi+Wtlo)^T; block = 4 waves, wave = 16 rows x 128 cols.
// A frag: lane row = l&15, k = (l>>4)*8..+7. B frag: Wt row n = nf*16 + (l&15).
// D: row = (l>>4)*4 + r, col = l&15 (dtype-independent layout, m89/m121).
// Writes f32 C (self-term reads) and fp16 Chi (gather table).
// Epilogue: als/ald[row,h] = <C_row_head, a_flat> via in-register dot + 16-lane shfl tree.
// HPC = heads per 128-col chunk (4 for C=32, 2 for C=64).
template<int HPC>
__global__ __launch_bounds__(256)
void gemm_mfma(const _Float16* __restrict__ Ahi, const _Float16* __restrict__ Alo,
               const _Float16* __restrict__ Wthi, const _Float16* __restrict__ Wtlo,
               float* __restrict__ C, _Float16* __restrict__ Chi,
               const float* __restrict__ aS, const float* __restrict__ aD,
               float* __restrict__ als, float* __restrict__ ald, int M)
{
    const int tid = threadIdx.x;
    const int wave = tid >> 6, lane = tid & 63;
    const int l15 = lane & 15, lk = lane >> 4;      // 0..3
    const int m0 = blockIdx.x * 64 + wave * 16;
    int mrow = m0 + l15;
    if (mrow >= M) mrow = M - 1;                     // clamp; stores guarded below

    f32x4 acc[8];
    #pragma unroll
    for (int i = 0; i < 8; ++i) acc[i] = (f32x4){0.f, 0.f, 0.f, 0.f};

    #pragma unroll
    for (int kt = 0; kt < 4; ++kt) {
        const int k = kt * 32 + lk * 8;
        half8v ah = *(const half8v*)&Ahi[(long long)mrow * 128 + k];
        half8v al = *(const half8v*)&Alo[(long long)mrow * 128 + k];
        #pragma unroll
        for (int nf = 0; nf < 8; ++nf) {
            half8v bh = *(const half8v*)&Wthi[(nf * 16 + l15) * 128 + k];
            half8v bl = *(const half8v*)&Wtlo[(nf * 16 + l15) * 128 + k];
            acc[nf] = __builtin_amdgcn_mfma_f32_16x16x32_f16(ah, bh, acc[nf], 0, 0, 0);
            acc[nf] = __builtin_amdgcn_mfma_f32_16x16x32_f16(ah, bl, acc[nf], 0, 0, 0);
            acc[nf] = __builtin_amdgcn_mfma_f32_16x16x32_f16(al, bh, acc[nf], 0, 0, 0);
        }
    }

    // store C (f32) and Chi (fp16)
    #pragma unroll
    for (int r = 0; r < 4; ++r) {
        int gm = m0 + lk * 4 + r;
        if (gm >= M) continue;
        #pragma unroll
        for (int nf = 0; nf < 8; ++nf) {
            C[(long long)gm * 128 + nf * 16 + l15] = acc[nf][r];
            Chi[(long long)gm * 128 + nf * 16 + l15] = (_Float16)acc[nf][r];
        }
    }

    // fused node_att: col = nf*16 + l15, head = nf / (8/HPC)
    float asv[8], adv[8];
    #pragma unroll
    for (int nf = 0; nf < 8; ++nf) {
        asv[nf] = aS[nf * 16 + l15];
        adv[nf] = aD[nf * 16 + l15];
    }
    constexpr int NFH = 8 / HPC;   // acc regs per head
    #pragma unroll
    for (int r = 0; r < 4; ++r) {
        #pragma unroll
        for (int h = 0; h < HPC; ++h) {
            float ps = 0.f, pd = 0.f;
            #pragma unroll
            for (int q = 0; q < NFH; ++q) {
                int nf = h * NFH + q;
                ps += acc[nf][r] * asv[nf];
                pd += acc[nf][r] * adv[nf];
            }
            #pragma unroll
            for (int m = 1; m < 16; m <<= 1) {
                ps += __shfl_xor(ps, m);
                pd += __shfl_xor(pd, m);
            }
            if (l15 == 0) {
                int gm = m0 + lk * 4 + r;
                if (gm < M) {
                    als[gm * HPC + h] = ps;
                    ald[gm * HPC + h] = pd;
                }
            }
        }
    }
}

// ---------------- fused aggregate: one wave per dst node, batch-8 fp16 gather ----------------
// ROW = HL*C = 128; lane owns 2 cols at j = lane*2; neighbor rows from fp16 h16,
// self row from f32 h32 (exact).
// concat (MEAN=false): elu(vec/denom + bias) -> fp16 hi/lo (next GEMM input)
// mean   (MEAN=true) : out[d] (+)= 0.25 * headpair_sum(vec/denom) (+ bias if ACCUM)
template<int C, int HL, bool MEAN, bool ACCUM>
__global__ __launch_bounds__(256)
void gat_aggregate(const int* __restrict__ rowptr, const int* __restrict__ csr_src,
                   const float* __restrict__ als, const float* __restrict__ ald,
                   const float* __restrict__ h32, const _Float16* __restrict__ h16,
                   const float* __restrict__ bias, float* __restrict__ out,
                   _Float16* __restrict__ ohi, _Float16* __restrict__ olo, int N)
{
    constexpr int ROW = HL * C;   // 128
    constexpr int B = 8;          // ILP batch
    const int d = (blockIdx.x * blockDim.x + threadIdx.x) >> 6;
    const int lane = threadIdx.x & 63;
    if (d >= N) return;
    const int j = lane * 2;
    const int hh = j / C;

    const float ald_d = ald[d * HL + hh];
    const float wself = expf(lrelu(als[d * HL + hh] + ald_d));
    float denom = wself;
    float2 hv = *(const float2*)&h32[(long long)d * ROW + j];
    float vx = wself * hv.x, vy = wself * hv.y;

    const int e0 = rowptr[d], e1 = rowptr[d + 1];
    for (int base = e0; base < e1; base += B) {
        int    sv[B];
        float  av[B];
        half2v hb[B];
        #pragma unroll
        for (int i = 0; i < B; ++i) {
            int ee = base + i;
            sv[i] = csr_src[ee < e1 ? ee : e1 - 1];   // clamp; masked below
        }
        #pragma unroll
        for (int i = 0; i < B; ++i) av[i] = als[sv[i] * HL + hh];
        #pragma unroll
        for (int i = 0; i < B; ++i) hb[i] = *(const half2v*)&h16[(long long)sv[i] * ROW + j];
        #pragma unroll
        for (int i = 0; i < B; ++i) {
            float wv = expf(lrelu(av[i] + ald_d));
            wv = (base + i < e1) ? wv : 0.f;
            denom += wv;
            vx += wv * (float)hb[i].x;
            vy += wv * (float)hb[i].y;
        }
    }
    float inv = 1.f / denom;
    vx *= inv; vy *= inv;

    if (!MEAN) {
        vx += bias[j]; vy += bias[j + 1];
        vx = vx > 0.f ? vx : expf(vx) - 1.f;
        vy = vy > 0.f ? vy : expf(vy) - 1.f;
        hf2 rx = split_f16(vx), ry = split_f16(vy);
        half2v hi2, lo2;
        hi2.x = rx.hi; hi2.y = ry.hi;
        lo2.x = rx.lo; lo2.y = ry.lo;
        *(half2v*)&ohi[(long long)d * ROW + j] = hi2;
        *(half2v*)&olo[(long long)d * ROW + j] = lo2;
    } else {
        // HL=2, C=64: lane l and l+32 hold the same output col for heads 0/1
        vx = 0.25f * vx + __shfl_xor(0.25f * vx, 32);
        vy = 0.25f * vy + __shfl_xor(0.25f * vy, 32);
        if (lane < 32) {
            float* op = &out[(long long)d * C + j];
            if (ACCUM) { vx += op[0] + bias[j]; vy += op[1] + bias[j + 1]; }
            *(float2*)op = make_float2(vx, vy);
        }
    }
}

extern "C" void kernel_launch(void* const* d_in, const int* in_sizes, int n_in,
                              void* d_out, int out_size, void* d_ws, size_t ws_size,
                              hipStream_t stream)
{
    const float* x      = (const float*)d_in[0];
    const void*  ei     = d_in[1];
    const float* W1     = (const float*)d_in[2];
    const float* a_src1 = (const float*)d_in[3];
    const float* a_dst1 = (const float*)d_in[4];
    const float* b1     = (const float*)d_in[5];
    const float* W2     = (const float*)d_in[6];
    const float* a_src2 = (const float*)d_in[7];
    const float* a_dst2 = (const float*)d_in[8];
    const float* b2     = (const float*)d_in[9];
    const float* W3     = (const float*)d_in[10];
    const float* a_src3 = (const float*)d_in[11];
    const float* a_dst3 = (const float*)d_in[12];
    const float* b3     = (const float*)d_in[13];

    const int N = in_sizes[0] / 128;
    const int E = in_sizes[1] / 2;

    char* w = (char*)d_ws;
    auto alloc = [&](size_t bytes) {
        char* p = w;
        w += (bytes + 255) & ~(size_t)255;
        return p;
    };
    int*      flag    = (int*)     alloc(256);
    int*      deg     = (int*)     alloc((size_t)N * 4);
    int*      rowptr  = (int*)     alloc((size_t)(N + 1) * 4);
    int*      cursor  = (int*)     alloc((size_t)N * 4);
    int*      bsum    = (int*)     alloc(1024 * 4);
    int*      csr_src = (int*)     alloc((size_t)E * 4);
    float*    hbuf    = (float*)   alloc((size_t)N * 128 * 4);
    _Float16* hhi     = (_Float16*)alloc((size_t)N * 128 * 2);
    _Float16* xhi     = (_Float16*)alloc((size_t)N * 128 * 2);
    _Float16* xlo     = (_Float16*)alloc((size_t)N * 128 * 2);
    float*    als     = (float*)   alloc((size_t)N * 4 * 4);
    float*    ald     = (float*)   alloc((size_t)N * 4 * 4);
    _Float16* wthi    = (_Float16*)alloc(128 * 128 * 2);
    _Float16* wtlo    = (_Float16*)alloc(128 * 128 * 2);
    if ((size_t)(w - (char*)d_ws) > ws_size) {
        fill_sentinel<<<(out_size + 255) / 256, 256, 0, stream>>>((float*)d_out, out_size);
        return;
    }

    const int gb = 256;
    const int nb1024 = (N + 1023) / 1024;
    const int mb = (N + 63) / 64;                  // gemm blocks (64 rows each)
    const int ab = (N * 64 + gb - 1) / gb;         // aggregate: 1 wave/node
    auto blocks = [&](long long tot) { return (int)((tot + gb - 1) / gb); };

    // ---------------- CSR build ----------------
    detect_idx64<<<1, 256, 0, stream>>>((const int*)ei, flag);
    (void)hipMemsetAsync(deg, 0, (size_t)N * 4, stream);
    count_deg<<<blocks(E), gb, 0, stream>>>(ei, flag, deg, E);
    scanA<<<nb1024, gb, 0, stream>>>(deg, rowptr, bsum, N);
    scanB<<<1, 1024, 0, stream>>>(bsum, nb1024);
    scanC<<<nb1024, gb, 0, stream>>>(rowptr, cursor, bsum, N, E);
    fill_csr<<<blocks(E), gb, 0, stream>>>(ei, flag, cursor, csr_src, E);

    // layer-1 input -> fp16 hi/lo
    convert_hilo<<<blocks((long long)N * 32), gb, 0, stream>>>(x, xhi, xlo, (long long)N * 32);

    // ---------------- layer 1 ----------------
    convert_wt<<<64, gb, 0, stream>>>(W1, wthi, wtlo, 128, 0);
    gemm_mfma<4><<<mb, gb, 0, stream>>>(xhi, xlo, wthi, wtlo, hbuf, hhi,
                                        a_src1, a_dst1, als, ald, N);
    gat_aggregate<32, 4, false, false><<<ab, gb, 0, stream>>>(
        rowptr, csr_src, als, ald, hbuf, hhi, b1, nullptr, xhi, xlo, N);

    // ---------------- layer 2 ----------------
    convert_wt<<<64, gb, 0, stream>>>(W2, wthi, wtlo, 128, 0);
    gemm_mfma<4><<<mb, gb, 0, stream>>>(xhi, xlo, wthi, wtlo, hbuf, hhi,
                                        a_src2, a_dst2, als, ald, N);
    gat_aggregate<32, 4, false, false><<<ab, gb, 0, stream>>>(
        rowptr, csr_src, als, ald, hbuf, hhi, b2, nullptr, xhi, xlo, N);

    // ---------------- layer 3: two head-pair chunks into d_out ----------------
    convert_wt<<<64, gb, 0, stream>>>(W3, wthi, wtlo, 256, 0);
    gemm_mfma<2><<<mb, gb, 0, stream>>>(xhi, xlo, wthi, wtlo, hbuf, hhi,
                                        a_src3, a_dst3, als, ald, N);
    gat_aggregate<64, 2, true, false><<<ab, gb, 0, stream>>>(
        rowptr, csr_src, als, ald, hbuf, hhi, b3, (float*)d_out, nullptr, nullptr, N);

    convert_wt<<<64, gb, 0, stream>>>(W3, wthi, wtlo, 256, 128);
    gemm_mfma<2><<<mb, gb, 0, stream>>>(xhi, xlo, wthi, wtlo, hbuf, hhi,
                                        a_src3 + 128, a_dst3 + 128, als, ald, N);
    gat_aggregate<64, 2, true, true><<<ab, gb, 0, stream>>>(
        rowptr, csr_src, als, ald, hbuf, hhi, b3, (float*)d_out, nullptr, nullptr, N);
}

// Round 8
// 710.954 us; speedup vs baseline: 18.0623x; 1.3192x over previous
//
#include <hip/hip_runtime.h>

// GAT 3-layer forward. CSR-by-dst aggregation (atomic-free fill via precomputed local
// offsets), fp16x2-split MFMA GEMM with fused node_att epilogue, fp16 gather tables,
// fast exp (v_exp_f32) throughout.
// Per layer: gemm_mfma (h = x@W -> fp16 h table + als/ald row-dots) -> gat_aggregate:
//   one WAVE per dst node: out = (sum w_e h16[src] + w_self h16[d]) / sum w.
// concat layers emit fp16 hi/lo (next GEMM input), layer 3 head-means into d_out.
// segment_max dropped: cancels exactly in alpha = e/denom; logits are O(+-3) here.

#define NEG_SLOPE 0.2f

typedef __attribute__((ext_vector_type(8))) _Float16 half8v;
typedef __attribute__((ext_vector_type(2))) _Float16 half2v;
typedef __attribute__((ext_vector_type(4))) float f32x4;

__device__ __forceinline__ float lrelu(float v) { return v > 0.f ? v : NEG_SLOPE * v; }

struct hf2 { _Float16 hi, lo; };
__device__ __forceinline__ hf2 split_f16(float f)
{
    hf2 r;
    r.hi = (_Float16)f;
    r.lo = (_Float16)(f - (float)r.hi);
    return r;
}

// ---------------- diagnostics: workspace overflow sentinel ----------------
__global__ void fill_sentinel(float* __restrict__ out, int n)
{
    int i = blockIdx.x * blockDim.x + threadIdx.x;
    if (i < n) out[i] = 1e30f;
}

// ---------------- edge-index dtype detection (int64 vs int32) ----------------
__global__ void detect_idx64(const int* __restrict__ ei, int* __restrict__ flag)
{
    __shared__ int anynz;
    if (threadIdx.x == 0) anynz = 0;
    __syncthreads();
    int v = ei[2 * threadIdx.x + 1];   // high words if int64 (all values < 2^31)
    if (v != 0) atomicOr(&anynz, 1);
    __syncthreads();
    if (threadIdx.x == 0) flag[0] = (anynz == 0) ? 1 : 0;   // 1 => int64
}

__global__ void convert_edges(const void* __restrict__ ei, const int* __restrict__ flag,
                              int* __restrict__ src32, int* __restrict__ dst32, int E)
{
    int e = blockIdx.x * blockDim.x + threadIdx.x;
    if (e >= E) return;
    if (flag[0]) {
        src32[e] = (int)((const long long*)ei)[e];
        dst32[e] = (int)((const long long*)ei)[E + e];
    } else {
        src32[e] = ((const int*)ei)[e];
        dst32[e] = ((const int*)ei)[E + e];
    }
}

// ---------------- CSR build ----------------
// count_deg: degree histogram + per-edge local offset (coalesced write)
__global__ void count_deg(const int* __restrict__ dst32, int* __restrict__ deg,
                          int* __restrict__ loc, int E)
{
    int e = blockIdx.x * blockDim.x + threadIdx.x;
    if (e >= E) return;
    loc[e] = atomicAdd(&deg[dst32[e]], 1);
}

__global__ __launch_bounds__(256)
void scanA(const int* __restrict__ deg, int* __restrict__ rowptr,
           int* __restrict__ bsum, int N)
{
    __shared__ int part[256];
    const int t = threadIdx.x;
    const int base = blockIdx.x * 1024 + t * 4;
    int v[4];
    #pragma unroll
    for (int j = 0; j < 4; ++j) v[j] = (base + j < N) ? deg[base + j] : 0;
    int s = v[0] + v[1] + v[2] + v[3];
    part[t] = s;
    __syncthreads();
    #pragma unroll
    for (int off = 1; off < 256; off <<= 1) {
        int p = (t >= off) ? part[t - off] : 0;
        __syncthreads();
        part[t] += p;
        __syncthreads();
    }
    int run = (t == 0) ? 0 : part[t - 1];
    #pragma unroll
    for (int j = 0; j < 4; ++j) {
        if (base + j < N) rowptr[base + j] = run;
        run += v[j];
    }
    if (t == 255) bsum[blockIdx.x] = part[255];
}

__global__ __launch_bounds__(1024)
void scanB(int* __restrict__ bsum, int nb)
{
    __shared__ int s[1024];
    int t = threadIdx.x;
    s[t] = (t < nb) ? bsum[t] : 0;
    __syncthreads();
    for (int off = 1; off < 1024; off <<= 1) {
        int p = (t >= off) ? s[t - off] : 0;
        __syncthreads();
        s[t] += p;
        __syncthreads();
    }
    if (t < nb) bsum[t] = (t == 0) ? 0 : s[t - 1];
}

__global__ __launch_bounds__(256)
void scanC(int* __restrict__ rowptr, const int* __restrict__ bsum, int N, int E)
{
    const int base = blockIdx.x * 1024 + threadIdx.x * 4;
    const int off = bsum[blockIdx.x];
    #pragma unroll
    for (int j = 0; j < 4; ++j)
        if (base + j < N) rowptr[base + j] += off;
    if (blockIdx.x == 0 && threadIdx.x == 0) rowptr[N] = E;
}

// fill_csr: pure scatter, no atomics (pos = rowptr[d] + loc[e])
__global__ void fill_csr(const int* __restrict__ src32, const int* __restrict__ dst32,
                         const int* __restrict__ loc, const int* __restrict__ rowptr,
                         int* __restrict__ csr_src, int E)
{
    int e = blockIdx.x * blockDim.x + threadIdx.x;
    if (e >= E) return;
    csr_src[rowptr[dst32[e]] + loc[e]] = src32[e];
}

// ---------------- f32 -> fp16 hi/lo converts ----------------
__global__ void convert_hilo(const float* __restrict__ in, _Float16* __restrict__ hi,
                             _Float16* __restrict__ lo, long long n4)
{
    long long t = (long long)blockIdx.x * blockDim.x + threadIdx.x;
    if (t >= n4) return;
    float4 v = *(const float4*)&in[t * 4];
    hf2 a = split_f16(v.x), b = split_f16(v.y), c = split_f16(v.z), d = split_f16(v.w);
    __attribute__((ext_vector_type(4))) _Float16 h, l;
    h.x = a.hi; h.y = b.hi; h.z = c.hi; h.w = d.hi;
    l.x = a.lo; l.y = b.lo; l.z = c.lo; l.w = d.lo;
    *(decltype(h)*)&hi[t * 4] = h;
    *(decltype(l)*)&lo[t * 4] = l;
}

// W chunk [128 k][128 n] -> transposed Wt_hi/lo [n][k] fp16
__global__ __launch_bounds__(256)
void convert_wt(const float* __restrict__ W, _Float16* __restrict__ wthi,
                _Float16* __restrict__ wtlo, int ldw, int wcol0)
{
    int t = blockIdx.x * 256 + threadIdx.x;   // 16384 threads
    int k = t >> 7, n = t & 127;
    float v = W[(long long)k * ldw + wcol0 + n];
    hf2 r = split_f16(v);
    wthi[n * 128 + k] = r.hi;
    wtlo[n * 128 + k] = r.lo;
}

// ---------------- MFMA GEMM + fused node_att epilogue ----------------
// h[M][128] fp16 = (Ahi+Alo) @ (Wthi+Wtlo)^T; block = 4 waves, wave = 16 rows x 128 cols.
// A frag: lane row = l&15, k = (l>>4)*8..+7. B frag: Wt row n = nf*16 + (l&15).
// D: row = (l>>4)*4 + r, col = l&15 (dtype-independent layout, m89/m121).
// Epilogue: als/ald[row,h] = <C_row_head, a_flat> via in-register dot + 16-lane shfl tree.
// HPC = heads per 128-col chunk (4 for C=32, 2 for C=64).
template<int HPC>
__global__ __launch_bounds__(256)
void gemm_mfma(const _Float16* __restrict__ Ahi, const _Float16* __restrict__ Alo,
               const _Float16* __restrict__ Wthi, const _Float16* __restrict__ Wtlo,
               _Float16* __restrict__ Chi,
               const float* __restrict__ aS, const float* __restrict__ aD,
               float* __restrict__ als, float* __restrict__ ald, int M)
{
    const int tid = threadIdx.x;
    const int wave = tid >> 6, lane = tid & 63;
    const int l15 = lane & 15, lk = lane >> 4;      // 0..3
    const int m0 = blockIdx.x * 64 + wave * 16;
    int mrow = m0 + l15;
    if (mrow >= M) mrow = M - 1;                     // clamp; stores guarded below

    f32x4 acc[8];
    #pragma unroll
    for (int i = 0; i < 8; ++i) acc[i] = (f32x4){0.f, 0.f, 0.f, 0.f};

    #pragma unroll
    for (int kt = 0; kt < 4; ++kt) {
        const int k = kt * 32 + lk * 8;
        half8v ah = *(const half8v*)&Ahi[(long long)mrow * 128 + k];
        half8v al = *(const half8v*)&Alo[(long long)mrow * 128 + k];
        #pragma unroll
        for (int nf = 0; nf < 8; ++nf) {
            half8v bh = *(const half8v*)&Wthi[(nf * 16 + l15) * 128 + k];
            half8v bl = *(const half8v*)&Wtlo[(nf * 16 + l15) * 128 + k];
            acc[nf] = __builtin_amdgcn_mfma_f32_16x16x32_f16(ah, bh, acc[nf], 0, 0, 0);
            acc[nf] = __builtin_amdgcn_mfma_f32_16x16x32_f16(ah, bl, acc[nf], 0, 0, 0);
            acc[nf] = __builtin_amdgcn_mfma_f32_16x16x32_f16(al, bh, acc[nf], 0, 0, 0);
        }
    }

    // store h (fp16)
    #pragma unroll
    for (int r = 0; r < 4; ++r) {
        int gm = m0 + lk * 4 + r;
        if (gm >= M) continue;
        #pragma unroll
        for (int nf = 0; nf < 8; ++nf)
            Chi[(long long)gm * 128 + nf * 16 + l15] = (_Float16)acc[nf][r];
    }

    // fused node_att: col = nf*16 + l15, head = nf / (8/HPC)
    float asv[8], adv[8];
    #pragma unroll
    for (int nf = 0; nf < 8; ++nf) {
        asv[nf] = aS[nf * 16 + l15];
        adv[nf] = aD[nf * 16 + l15];
    }
    constexpr int NFH = 8 / HPC;   // acc regs per head
    #pragma unroll
    for (int r = 0; r < 4; ++r) {
        #pragma unroll
        for (int h = 0; h < HPC; ++h) {
            float ps = 0.f, pd = 0.f;
            #pragma unroll
            for (int q = 0; q < NFH; ++q) {
                int nf = h * NFH + q;
                ps += acc[nf][r] * asv[nf];
                pd += acc[nf][r] * adv[nf];
            }
            #pragma unroll
            for (int m = 1; m < 16; m <<= 1) {
                ps += __shfl_xor(ps, m);
                pd += __shfl_xor(pd, m);
            }
            if (l15 == 0) {
                int gm = m0 + lk * 4 + r;
                if (gm < M) {
                    als[gm * HPC + h] = ps;
                    ald[gm * HPC + h] = pd;
                }
            }
        }
    }
}

// ---------------- fused aggregate: one wave per dst node, batch-8 fp16 gather ----------------
// ROW = HL*C = 128; lane owns 2 cols at j = lane*2; all rows from fp16 h16.
// concat (MEAN=false): elu(vec/denom + bias) -> fp16 hi/lo (next GEMM input)
// mean   (MEAN=true) : out[d] (+)= 0.25 * headpair_sum(vec/denom) (+ bias if ACCUM)
template<int C, int HL, bool MEAN, bool ACCUM>
__global__ __launch_bounds__(256)
void gat_aggregate(const int* __restrict__ rowptr, const int* __restrict__ csr_src,
                   const float* __restrict__ als, const float* __restrict__ ald,
                   const _Float16* __restrict__ h16, const float* __restrict__ bias,
                   float* __restrict__ out,
                   _Float16* __restrict__ ohi, _Float16* __restrict__ olo, int N)
{
    constexpr int ROW = HL * C;   // 128
    constexpr int B = 8;          // ILP batch
    const int d = (blockIdx.x * blockDim.x + threadIdx.x) >> 6;
    const int lane = threadIdx.x & 63;
    if (d >= N) return;
    const int j = lane * 2;
    const int hh = j / C;

    const float ald_d = ald[d * HL + hh];
    const float wself = __expf(lrelu(als[d * HL + hh] + ald_d));
    float denom = wself;
    half2v hv = *(const half2v*)&h16[(unsigned)d * ROW + j];
    float vx = wself * (float)hv.x, vy = wself * (float)hv.y;

    const int e0 = rowptr[d], e1 = rowptr[d + 1];
    for (int base = e0; base < e1; base += B) {
        int    sv[B];
        float  av[B];
        half2v hb[B];
        #pragma unroll
        for (int i = 0; i < B; ++i) {
            int ee = base + i;
            sv[i] = csr_src[ee < e1 ? ee : e1 - 1];   // clamp; masked below
        }
        #pragma unroll
        for (int i = 0; i < B; ++i) av[i] = als[sv[i] * HL + hh];
        #pragma unroll
        for (int i = 0; i < B; ++i) hb[i] = *(const half2v*)&h16[(unsigned)sv[i] * ROW + j];
        #pragma unroll
        for (int i = 0; i < B; ++i) {
            float wv = __expf(lrelu(av[i] + ald_d));
            wv = (base + i < e1) ? wv : 0.f;
            denom += wv;
            vx += wv * (float)hb[i].x;
            vy += wv * (float)hb[i].y;
        }
    }
    float inv = 1.f / denom;
    vx *= inv; vy *= inv;

    if (!MEAN) {
        vx += bias[j]; vy += bias[j + 1];
        vx = vx > 0.f ? vx : __expf(vx) - 1.f;
        vy = vy > 0.f ? vy : __expf(vy) - 1.f;
        hf2 rx = split_f16(vx), ry = split_f16(vy);
        half2v hi2, lo2;
        hi2.x = rx.hi; hi2.y = ry.hi;
        lo2.x = rx.lo; lo2.y = ry.lo;
        *(half2v*)&ohi[(unsigned)d * ROW + j] = hi2;
        *(half2v*)&olo[(unsigned)d * ROW + j] = lo2;
    } else {
        // HL=2, C=64: lane l and l+32 hold the same output col for heads 0/1
        vx = 0.25f * vx + __shfl_xor(0.25f * vx, 32);
        vy = 0.25f * vy + __shfl_xor(0.25f * vy, 32);
        if (lane < 32) {
            float* op = &out[(unsigned)d * C + j];
            if (ACCUM) { vx += op[0] + bias[j]; vy += op[1] + bias[j + 1]; }
            *(float2*)op = make_float2(vx, vy);
        }
    }
}

extern "C" void kernel_launch(void* const* d_in, const int* in_sizes, int n_in,
                              void* d_out, int out_size, void* d_ws, size_t ws_size,
                              hipStream_t stream)
{
    const float* x      = (const float*)d_in[0];
    const void*  ei     = d_in[1];
    const float* W1     = (const float*)d_in[2];
    const float* a_src1 = (const float*)d_in[3];
    const float* a_dst1 = (const float*)d_in[4];
    const float* b1     = (const float*)d_in[5];
    const float* W2     = (const float*)d_in[6];
    const float* a_src2 = (const float*)d_in[7];
    const float* a_dst2 = (const float*)d_in[8];
    const float* b2     = (const float*)d_in[9];
    const float* W3     = (const float*)d_in[10];
    const float* a_src3 = (const float*)d_in[11];
    const float* a_dst3 = (const float*)d_in[12];
    const float* b3     = (const float*)d_in[13];

    const int N = in_sizes[0] / 128;
    const int E = in_sizes[1] / 2;

    char* w = (char*)d_ws;
    auto alloc = [&](size_t bytes) {
        char* p = w;
        w += (bytes + 255) & ~(size_t)255;
        return p;
    };
    int*      flag    = (int*)     alloc(256);
    int*      deg     = (int*)     alloc((size_t)N * 4);
    int*      rowptr  = (int*)     alloc((size_t)(N + 1) * 4);
    int*      bsum    = (int*)     alloc(1024 * 4);
    int*      src32   = (int*)     alloc((size_t)E * 4);
    int*      dst32   = (int*)     alloc((size_t)E * 4);
    int*      loc     = (int*)     alloc((size_t)E * 4);
    int*      csr_src = (int*)     alloc((size_t)E * 4);
    _Float16* hhi     = (_Float16*)alloc((size_t)N * 128 * 2);
    _Float16* xhi     = (_Float16*)alloc((size_t)N * 128 * 2);
    _Float16* xlo     = (_Float16*)alloc((size_t)N * 128 * 2);
    float*    als     = (float*)   alloc((size_t)N * 4 * 4);
    float*    ald     = (float*)   alloc((size_t)N * 4 * 4);
    _Float16* wthi    = (_Float16*)alloc(128 * 128 * 2);
    _Float16* wtlo    = (_Float16*)alloc(128 * 128 * 2);
    if ((size_t)(w - (char*)d_ws) > ws_size) {
        fill_sentinel<<<(out_size + 255) / 256, 256, 0, stream>>>((float*)d_out, out_size);
        return;
    }

    const int gb = 256;
    const int nb1024 = (N + 1023) / 1024;
    const int mb = (N + 63) / 64;                  // gemm blocks (64 rows each)
    const int ab = (N * 64 + gb - 1) / gb;         // aggregate: 1 wave/node
    auto blocks = [&](long long tot) { return (int)((tot + gb - 1) / gb); };

    // ---------------- CSR build ----------------
    detect_idx64<<<1, 256, 0, stream>>>((const int*)ei, flag);
    convert_edges<<<blocks(E), gb, 0, stream>>>(ei, flag, src32, dst32, E);
    (void)hipMemsetAsync(deg, 0, (size_t)N * 4, stream);
    count_deg<<<blocks(E), gb, 0, stream>>>(dst32, deg, loc, E);
    scanA<<<nb1024, gb, 0, stream>>>(deg, rowptr, bsum, N);
    scanB<<<1, 1024, 0, stream>>>(bsum, nb1024);
    scanC<<<nb1024, gb, 0, stream>>>(rowptr, bsum, N, E);
    fill_csr<<<blocks(E), gb, 0, stream>>>(src32, dst32, loc, rowptr, csr_src, E);

    // layer-1 input -> fp16 hi/lo
    convert_hilo<<<blocks((long long)N * 32), gb, 0, stream>>>(x, xhi, xlo, (long long)N * 32);

    // ---------------- layer 1 ----------------
    convert_wt<<<64, gb, 0, stream>>>(W1, wthi, wtlo, 128, 0);
    gemm_mfma<4><<<mb, gb, 0, stream>>>(xhi, xlo, wthi, wtlo, hhi,
                                        a_src1, a_dst1, als, ald, N);
    gat_aggregate<32, 4, false, false><<<ab, gb, 0, stream>>>(
        rowptr, csr_src, als, ald, hhi, b1, nullptr, xhi, xlo, N);

    // ---------------- layer 2 ----------------
    convert_wt<<<64, gb, 0, stream>>>(W2, wthi, wtlo, 128, 0);
    gemm_mfma<4><<<mb, gb, 0, stream>>>(xhi, xlo, wthi, wtlo, hhi,
                                        a_src2, a_dst2, als, ald, N);
    gat_aggregate<32, 4, false, false><<<ab, gb, 0, stream>>>(
        rowptr, csr_src, als, ald, hhi, b2, nullptr, xhi, xlo, N);

    // ---------------- layer 3: two head-pair chunks into d_out ----------------
    convert_wt<<<64, gb, 0, stream>>>(W3, wthi, wtlo, 256, 0);
    gemm_mfma<2><<<mb, gb, 0, stream>>>(xhi, xlo, wthi, wtlo, hhi,
                                        a_src3, a_dst3, als, ald, N);
    gat_aggregate<64, 2, true, false><<<ab, gb, 0, stream>>>(
        rowptr, csr_src, als, ald, hhi, b3, (float*)d_out, nullptr, nullptr, N);

    convert_wt<<<64, gb, 0, stream>>>(W3, wthi, wtlo, 256, 128);
    gemm_mfma<2><<<mb, gb, 0, stream>>>(xhi, xlo, wthi, wtlo, hhi,
                                        a_src3 + 128, a_dst3 + 128, als, ald, N);
    gat_aggregate<64, 2, true, true><<<ab, gb, 0, stream>>>(
        rowptr, csr_src, als, ald, hhi, b3, (float*)d_out, nullptr, nullptr, N);
}

// Round 9
// 694.786 us; speedup vs baseline: 18.4826x; 1.0233x over previous
//
#include <hip/hip_runtime.h>

// GAT 3-layer forward. CSR-by-dst aggregation: per batch of 8 edges, lanes 0..8*HL-1
// compute w(edge,head) ONCE (1 als gather + 1 exp each); all 64 lanes get sv/w via
// __shfl broadcast (LDS pipe) -> ~3x VALU cut vs per-lane recompute.
// fp16x2-split MFMA GEMM with fused node_att epilogue; fp16 gather tables; fast exp.
// segment_max dropped: cancels exactly in alpha = e/denom; logits are O(+-3) here.

#define NEG_SLOPE 0.2f

typedef __attribute__((ext_vector_type(8))) _Float16 half8v;
typedef __attribute__((ext_vector_type(2))) _Float16 half2v;
typedef __attribute__((ext_vector_type(4))) float f32x4;

__device__ __forceinline__ float lrelu(float v) { return v > 0.f ? v : NEG_SLOPE * v; }

struct hf2 { _Float16 hi, lo; };
__device__ __forceinline__ hf2 split_f16(float f)
{
    hf2 r;
    r.hi = (_Float16)f;
    r.lo = (_Float16)(f - (float)r.hi);
    return r;
}

// ---------------- diagnostics: workspace overflow sentinel ----------------
__global__ void fill_sentinel(float* __restrict__ out, int n)
{
    int i = blockIdx.x * blockDim.x + threadIdx.x;
    if (i < n) out[i] = 1e30f;
}

// ---------------- edge-index dtype detection (int64 vs int32) ----------------
__global__ void detect_idx64(const int* __restrict__ ei, int* __restrict__ flag)
{
    __shared__ int anynz;
    if (threadIdx.x == 0) anynz = 0;
    __syncthreads();
    int v = ei[2 * threadIdx.x + 1];   // high words if int64 (all values < 2^31)
    if (v != 0) atomicOr(&anynz, 1);
    __syncthreads();
    if (threadIdx.x == 0) flag[0] = (anynz == 0) ? 1 : 0;   // 1 => int64
}

__global__ void convert_edges(const void* __restrict__ ei, const int* __restrict__ flag,
                              int* __restrict__ src32, int* __restrict__ dst32, int E)
{
    int e = blockIdx.x * blockDim.x + threadIdx.x;
    if (e >= E) return;
    if (flag[0]) {
        src32[e] = (int)((const long long*)ei)[e];
        dst32[e] = (int)((const long long*)ei)[E + e];
    } else {
        src32[e] = ((const int*)ei)[e];
        dst32[e] = ((const int*)ei)[E + e];
    }
}

// ---------------- CSR build ----------------
__global__ void count_deg(const int* __restrict__ dst32, int* __restrict__ deg,
                          int* __restrict__ loc, int E)
{
    int e = blockIdx.x * blockDim.x + threadIdx.x;
    if (e >= E) return;
    loc[e] = atomicAdd(&deg[dst32[e]], 1);
}

__global__ __launch_bounds__(256)
void scanA(const int* __restrict__ deg, int* __restrict__ rowptr,
           int* __restrict__ bsum, int N)
{
    __shared__ int part[256];
    const int t = threadIdx.x;
    const int base = blockIdx.x * 1024 + t * 4;
    int v[4];
    #pragma unroll
    for (int j = 0; j < 4; ++j) v[j] = (base + j < N) ? deg[base + j] : 0;
    int s = v[0] + v[1] + v[2] + v[3];
    part[t] = s;
    __syncthreads();
    #pragma unroll
    for (int off = 1; off < 256; off <<= 1) {
        int p = (t >= off) ? part[t - off] : 0;
        __syncthreads();
        part[t] += p;
        __syncthreads();
    }
    int run = (t == 0) ? 0 : part[t - 1];
    #pragma unroll
    for (int j = 0; j < 4; ++j) {
        if (base + j < N) rowptr[base + j] = run;
        run += v[j];
    }
    if (t == 255) bsum[blockIdx.x] = part[255];
}

__global__ __launch_bounds__(1024)
void scanB(int* __restrict__ bsum, int nb)
{
    __shared__ int s[1024];
    int t = threadIdx.x;
    s[t] = (t < nb) ? bsum[t] : 0;
    __syncthreads();
    for (int off = 1; off < 1024; off <<= 1) {
        int p = (t >= off) ? s[t - off] : 0;
        __syncthreads();
        s[t] += p;
        __syncthreads();
    }
    if (t < nb) bsum[t] = (t == 0) ? 0 : s[t - 1];
}

__global__ __launch_bounds__(256)
void scanC(int* __restrict__ rowptr, const int* __restrict__ bsum, int N, int E)
{
    const int base = blockIdx.x * 1024 + threadIdx.x * 4;
    const int off = bsum[blockIdx.x];
    #pragma unroll
    for (int j = 0; j < 4; ++j)
        if (base + j < N) rowptr[base + j] += off;
    if (blockIdx.x == 0 && threadIdx.x == 0) rowptr[N] = E;
}

__global__ void fill_csr(const int* __restrict__ src32, const int* __restrict__ dst32,
                         const int* __restrict__ loc, const int* __restrict__ rowptr,
                         int* __restrict__ csr_src, int E)
{
    int e = blockIdx.x * blockDim.x + threadIdx.x;
    if (e >= E) return;
    csr_src[rowptr[dst32[e]] + loc[e]] = src32[e];
}

// ---------------- f32 -> fp16 hi/lo converts ----------------
__global__ void convert_hilo(const float* __restrict__ in, _Float16* __restrict__ hi,
                             _Float16* __restrict__ lo, long long n4)
{
    long long t = (long long)blockIdx.x * blockDim.x + threadIdx.x;
    if (t >= n4) return;
    float4 v = *(const float4*)&in[t * 4];
    hf2 a = split_f16(v.x), b = split_f16(v.y), c = split_f16(v.z), d = split_f16(v.w);
    __attribute__((ext_vector_type(4))) _Float16 h, l;
    h.x = a.hi; h.y = b.hi; h.z = c.hi; h.w = d.hi;
    l.x = a.lo; l.y = b.lo; l.z = c.lo; l.w = d.lo;
    *(decltype(h)*)&hi[t * 4] = h;
    *(decltype(l)*)&lo[t * 4] = l;
}

// W chunk [128 k][128 n] -> transposed Wt_hi/lo [n][k] fp16
__global__ __launch_bounds__(256)
void convert_wt(const float* __restrict__ W, _Float16* __restrict__ wthi,
                _Float16* __restrict__ wtlo, int ldw, int wcol0)
{
    int t = blockIdx.x * 256 + threadIdx.x;   // 16384 threads
    int k = t >> 7, n = t & 127;
    float v = W[(long long)k * ldw + wcol0 + n];
    hf2 r = split_f16(v);
    wthi[n * 128 + k] = r.hi;
    wtlo[n * 128 + k] = r.lo;
}

// ---------------- MFMA GEMM + fused node_att epilogue ----------------
// h[M][128] fp16 = (Ahi+Alo) @ (Wthi+Wtlo)^T; block = 4 waves, wave = 16 rows x 128 cols.
// A frag: lane row = l&15, k = (l>>4)*8..+7. B frag: Wt row n = nf*16 + (l&15).
// D: row = (l>>4)*4 + r, col = l&15 (dtype-independent layout, m89/m121).
// Epilogue: als/ald[row,h] = <C_row_head, a_flat> via in-register dot + 16-lane shfl tree.
template<int HPC>
__global__ __launch_bounds__(256)
void gemm_mfma(const _Float16* __restrict__ Ahi, const _Float16* __restrict__ Alo,
               const _Float16* __restrict__ Wthi, const _Float16* __restrict__ Wtlo,
               _Float16* __restrict__ Chi,
               const float* __restrict__ aS, const float* __restrict__ aD,
               float* __restrict__ als, float* __restrict__ ald, int M)
{
    const int tid = threadIdx.x;
    const int wave = tid >> 6, lane = tid & 63;
    const int l15 = lane & 15, lk = lane >> 4;      // 0..3
    const int m0 = blockIdx.x * 64 + wave * 16;
    int mrow = m0 + l15;
    if (mrow >= M) mrow = M - 1;                     // clamp; stores guarded below

    f32x4 acc[8];
    #pragma unroll
    for (int i = 0; i < 8; ++i) acc[i] = (f32x4){0.f, 0.f, 0.f, 0.f};

    #pragma unroll
    for (int kt = 0; kt < 4; ++kt) {
        const int k = kt * 32 + lk * 8;
        half8v ah = *(const half8v*)&Ahi[(long long)mrow * 128 + k];
        half8v al = *(const half8v*)&Alo[(long long)mrow * 128 + k];
        #pragma unroll
        for (int nf = 0; nf < 8; ++nf) {
            half8v bh = *(const half8v*)&Wthi[(nf * 16 + l15) * 128 + k];
            half8v bl = *(const half8v*)&Wtlo[(nf * 16 + l15) * 128 + k];
            acc[nf] = __builtin_amdgcn_mfma_f32_16x16x32_f16(ah, bh, acc[nf], 0, 0, 0);
            acc[nf] = __builtin_amdgcn_mfma_f32_16x16x32_f16(ah, bl, acc[nf], 0, 0, 0);
            acc[nf] = __builtin_amdgcn_mfma_f32_16x16x32_f16(al, bh, acc[nf], 0, 0, 0);
        }
    }

    // store h (fp16)
    #pragma unroll
    for (int r = 0; r < 4; ++r) {
        int gm = m0 + lk * 4 + r;
        if (gm >= M) continue;
        #pragma unroll
        for (int nf = 0; nf < 8; ++nf)
            Chi[(long long)gm * 128 + nf * 16 + l15] = (_Float16)acc[nf][r];
    }

    // fused node_att: col = nf*16 + l15, head = nf / (8/HPC)
    float asv[8], adv[8];
    #pragma unroll
    for (int nf = 0; nf < 8; ++nf) {
        asv[nf] = aS[nf * 16 + l15];
        adv[nf] = aD[nf * 16 + l15];
    }
    constexpr int NFH = 8 / HPC;   // acc regs per head
    #pragma unroll
    for (int r = 0; r < 4; ++r) {
        #pragma unroll
        for (int h = 0; h < HPC; ++h) {
            float ps = 0.f, pd = 0.f;
            #pragma unroll
            for (int q = 0; q < NFH; ++q) {
                int nf = h * NFH + q;
                ps += acc[nf][r] * asv[nf];
                pd += acc[nf][r] * adv[nf];
            }
            #pragma unroll
            for (int m = 1; m < 16; m <<= 1) {
                ps += __shfl_xor(ps, m);
                pd += __shfl_xor(pd, m);
            }
            if (l15 == 0) {
                int gm = m0 + lk * 4 + r;
                if (gm < M) {
                    als[gm * HPC + h] = ps;
                    ald[gm * HPC + h] = pd;
                }
            }
        }
    }
}

// ---------------- fused aggregate: one wave per dst node, shfl-broadcast w ----------------
// ROW = HL*C = 128; lane owns 2 cols at j = lane*2.
// Per batch of 8 edges: lane i*HL+h computes w(edge i, head h) once; sv and w are
// broadcast to all lanes via __shfl. Tail masking folded into the computing lane.
// concat (MEAN=false): elu(vec/denom + bias) -> fp16 hi/lo (next GEMM input)
// mean   (MEAN=true) : out[d] (+)= 0.25 * headpair_sum(vec/denom) (+ bias if ACCUM)
template<int C, int HL, bool MEAN, bool ACCUM>
__global__ __launch_bounds__(256)
void gat_aggregate(const int* __restrict__ rowptr, const int* __restrict__ csr_src,
                   const float* __restrict__ als, const float* __restrict__ ald,
                   const _Float16* __restrict__ h16, const float* __restrict__ bias,
                   float* __restrict__ out,
                   _Float16* __restrict__ ohi, _Float16* __restrict__ olo, int N)
{
    constexpr int ROW = HL * C;            // 128
    constexpr int LOG2HL = (HL == 4) ? 2 : 1;
    const int d = (blockIdx.x * blockDim.x + threadIdx.x) >> 6;
    const int lane = threadIdx.x & 63;
    if (d >= N) return;
    const int j = lane * 2;
    const int hh = j / C;                  // consumer head

    const int myh = lane & (HL - 1);       // producer (edge, head) assignment
    const int myi = lane >> LOG2HL;
    const float ald_mine = ald[d * HL + myh];

    const float ald_d = (HL == 4 && myh == hh) ? ald_mine : ald[d * HL + hh];
    const float wself = __expf(lrelu(als[d * HL + hh] + ald_d));
    float denom = wself;
    half2v hv = *(const half2v*)&h16[(unsigned)d * ROW + j];
    float vx = wself * (float)hv.x, vy = wself * (float)hv.y;

    const int e0 = rowptr[d], e1 = rowptr[d + 1];
    for (int base = e0; base < e1; base += 8) {
        // producer: one (edge, head) per lane (lanes 0..8*HL-1 meaningful)
        int ee = base + myi;
        int sv_mine = csr_src[ee < e1 ? ee : e1 - 1];
        float a = als[sv_mine * HL + myh] + ald_mine;
        float w_mine = (ee < e1) ? __expf(lrelu(a)) : 0.f;

        // broadcast sv, gather rows (batched for ILP), then broadcast w + FMA
        int sref[8];
        half2v hb[8];
        #pragma unroll
        for (int i = 0; i < 8; ++i) sref[i] = __shfl(sv_mine, i * HL, 64);
        #pragma unroll
        for (int i = 0; i < 8; ++i) hb[i] = *(const half2v*)&h16[(unsigned)sref[i] * ROW + j];
        #pragma unroll
        for (int i = 0; i < 8; ++i) {
            float wv = __shfl(w_mine, i * HL + hh, 64);
            denom += wv;
            vx += wv * (float)hb[i].x;
            vy += wv * (float)hb[i].y;
        }
    }
    float inv = 1.f / denom;
    vx *= inv; vy *= inv;

    if (!MEAN) {
        vx += bias[j]; vy += bias[j + 1];
        vx = vx > 0.f ? vx : __expf(vx) - 1.f;
        vy = vy > 0.f ? vy : __expf(vy) - 1.f;
        hf2 rx = split_f16(vx), ry = split_f16(vy);
        half2v hi2, lo2;
        hi2.x = rx.hi; hi2.y = ry.hi;
        lo2.x = rx.lo; lo2.y = ry.lo;
        *(half2v*)&ohi[(unsigned)d * ROW + j] = hi2;
        *(half2v*)&olo[(unsigned)d * ROW + j] = lo2;
    } else {
        // HL=2, C=64: lane l and l+32 hold the same output col for heads 0/1
        vx = 0.25f * vx + __shfl_xor(0.25f * vx, 32);
        vy = 0.25f * vy + __shfl_xor(0.25f * vy, 32);
        if (lane < 32) {
            float* op = &out[(unsigned)d * C + j];
            if (ACCUM) { vx += op[0] + bias[j]; vy += op[1] + bias[j + 1]; }
            *(float2*)op = make_float2(vx, vy);
        }
    }
}

extern "C" void kernel_launch(void* const* d_in, const int* in_sizes, int n_in,
                              void* d_out, int out_size, void* d_ws, size_t ws_size,
                              hipStream_t stream)
{
    const float* x      = (const float*)d_in[0];
    const void*  ei     = d_in[1];
    const float* W1     = (const float*)d_in[2];
    const float* a_src1 = (const float*)d_in[3];
    const float* a_dst1 = (const float*)d_in[4];
    const float* b1     = (const float*)d_in[5];
    const float* W2     = (const float*)d_in[6];
    const float* a_src2 = (const float*)d_in[7];
    const float* a_dst2 = (const float*)d_in[8];
    const float* b2     = (const float*)d_in[9];
    const float* W3     = (const float*)d_in[10];
    const float* a_src3 = (const float*)d_in[11];
    const float* a_dst3 = (const float*)d_in[12];
    const float* b3     = (const float*)d_in[13];

    const int N = in_sizes[0] / 128;
    const int E = in_sizes[1] / 2;

    char* w = (char*)d_ws;
    auto alloc = [&](size_t bytes) {
        char* p = w;
        w += (bytes + 255) & ~(size_t)255;
        return p;
    };
    int*      flag    = (int*)     alloc(256);
    int*      deg     = (int*)     alloc((size_t)N * 4);
    int*      rowptr  = (int*)     alloc((size_t)(N + 1) * 4);
    int*      bsum    = (int*)     alloc(1024 * 4);
    int*      src32   = (int*)     alloc((size_t)E * 4);
    int*      dst32   = (int*)     alloc((size_t)E * 4);
    int*      loc     = (int*)     alloc((size_t)E * 4);
    int*      csr_src = (int*)     alloc((size_t)E * 4);
    _Float16* hhi     = (_Float16*)alloc((size_t)N * 128 * 2);
    _Float16* xhi     = (_Float16*)alloc((size_t)N * 128 * 2);
    _Float16* xlo     = (_Float16*)alloc((size_t)N * 128 * 2);
    float*    als     = (float*)   alloc((size_t)N * 4 * 4);
    float*    ald     = (float*)   alloc((size_t)N * 4 * 4);
    _Float16* wthi    = (_Float16*)alloc(128 * 128 * 2);
    _Float16* wtlo    = (_Float16*)alloc(128 * 128 * 2);
    if ((size_t)(w - (char*)d_ws) > ws_size) {
        fill_sentinel<<<(out_size + 255) / 256, 256, 0, stream>>>((float*)d_out, out_size);
        return;
    }

    const int gb = 256;
    const int nb1024 = (N + 1023) / 1024;
    const int mb = (N + 63) / 64;                  // gemm blocks (64 rows each)
    const int ab = (N * 64 + gb - 1) / gb;         // aggregate: 1 wave/node
    auto blocks = [&](long long tot) { return (int)((tot + gb - 1) / gb); };

    // ---------------- CSR build ----------------
    detect_idx64<<<1, 256, 0, stream>>>((const int*)ei, flag);
    convert_edges<<<blocks(E), gb, 0, stream>>>(ei, flag, src32, dst32, E);
    (void)hipMemsetAsync(deg, 0, (size_t)N * 4, stream);
    count_deg<<<blocks(E), gb, 0, stream>>>(dst32, deg, loc, E);
    scanA<<<nb1024, gb, 0, stream>>>(deg, rowptr, bsum, N);
    scanB<<<1, 1024, 0, stream>>>(bsum, nb1024);
    scanC<<<nb1024, gb, 0, stream>>>(rowptr, bsum, N, E);
    fill_csr<<<blocks(E), gb, 0, stream>>>(src32, dst32, loc, rowptr, csr_src, E);

    // layer-1 input -> fp16 hi/lo
    convert_hilo<<<blocks((long long)N * 32), gb, 0, stream>>>(x, xhi, xlo, (long long)N * 32);

    // ---------------- layer 1 ----------------
    convert_wt<<<64, gb, 0, stream>>>(W1, wthi, wtlo, 128, 0);
    gemm_mfma<4><<<mb, gb, 0, stream>>>(xhi, xlo, wthi, wtlo, hhi,
                                        a_src1, a_dst1, als, ald, N);
    gat_aggregate<32, 4, false, false><<<ab, gb, 0, stream>>>(
        rowptr, csr_src, als, ald, hhi, b1, nullptr, xhi, xlo, N);

    // ---------------- layer 2 ----------------
    convert_wt<<<64, gb, 0, stream>>>(W2, wthi, wtlo, 128, 0);
    gemm_mfma<4><<<mb, gb, 0, stream>>>(xhi, xlo, wthi, wtlo, hhi,
                                        a_src2, a_dst2, als, ald, N);
    gat_aggregate<32, 4, false, false><<<ab, gb, 0, stream>>>(
        rowptr, csr_src, als, ald, hhi, b2, nullptr, xhi, xlo, N);

    // ---------------- layer 3: two head-pair chunks into d_out ----------------
    convert_wt<<<64, gb, 0, stream>>>(W3, wthi, wtlo, 256, 0);
    gemm_mfma<2><<<mb, gb, 0, stream>>>(xhi, xlo, wthi, wtlo, hhi,
                                        a_src3, a_dst3, als, ald, N);
    gat_aggregate<64, 2, true, false><<<ab, gb, 0, stream>>>(
        rowptr, csr_src, als, ald, hhi, b3, (float*)d_out, nullptr, nullptr, N);

    convert_wt<<<64, gb, 0, stream>>>(W3, wthi, wtlo, 256, 128);
    gemm_mfma<2><<<mb, gb, 0, stream>>>(xhi, xlo, wthi, wtlo, hhi,
                                        a_src3 + 128, a_dst3 + 128, als, ald, N);
    gat_aggregate<64, 2, true, true><<<ab, gb, 0, stream>>>(
        rowptr, csr_src, als, ald, hhi, b3, (float*)d_out, nullptr, nullptr, N);
}